// Round 12
// baseline (427.976 us; speedup 1.0000x reference)
//
#include <hip/hip_runtime.h>
#include <hip/hip_bf16.h>
#include <math.h>

#define NTOK 4096
#define DIM  1024

typedef __attribute__((ext_vector_type(8))) short short8;   // 8 bf16 = 4 VGPR
typedef __attribute__((ext_vector_type(4))) float f32x4;

__device__ __forceinline__ short f2bf(float f) {
    return __builtin_bit_cast(short, __float2bfloat16(f));
}
__device__ __forceinline__ float bf2f(short s) {
    unsigned u = ((unsigned)(unsigned short)s) << 16;
    return __builtin_bit_cast(float, u);
}
__device__ __forceinline__ float gelu_exact(float x) {
    return x * 0.5f * (1.0f + erff(x * 0.70710678118654752f));
}

// ------- fused prep: X->bf16 + 6 transposes + compaction + exp(bias) ------
__device__ __forceinline__
void transpose_tile(const float* __restrict__ src, short* __restrict__ dst,
                    int K, int V, int Vpad, int vt, int kt)
{
    __shared__ float tile[32][33];
    const int v0 = vt * 32, k0 = kt * 32;
    const int tx = threadIdx.x & 31, ty = threadIdx.x >> 5;   // 32 x 8
    #pragma unroll
    for (int i = 0; i < 4; ++i) {
        const int k = k0 + ty + 8 * i, v = v0 + tx;
        tile[ty + 8 * i][tx] = (k < K && v < V) ? src[(size_t)k * V + v] : 0.f;
    }
    __syncthreads();
    #pragma unroll
    for (int i = 0; i < 4; ++i) {
        const int v = v0 + ty + 8 * i, k = k0 + tx;
        if (v < Vpad && k < K) dst[(size_t)v * K + k] = f2bf(tile[tx][ty + 8 * i]);
    }
}

__global__ __launch_bounds__(256)
void prep_kernel(const float* __restrict__ X, short* __restrict__ Xb,
                 const float* __restrict__ hp,  short* __restrict__ WhpT,
                 const float* __restrict__ t1p, short* __restrict__ W1pT,
                 const float* __restrict__ t2p, short* __restrict__ W2pT,
                 const float* __restrict__ hw,  short* __restrict__ WhT,
                 const float* __restrict__ t1w, short* __restrict__ W1T,
                 const float* __restrict__ t2w, short* __restrict__ W2T,
                 const int* __restrict__ labels,
                 int* __restrict__ idx1, int* __restrict__ idx2,
                 int* __restrict__ counts,
                 const float* __restrict__ t1b, const float* __restrict__ t2b,
                 float* __restrict__ eb1, float* __restrict__ eb2t)
{
    int b = blockIdx.x;
    if (b < 2048) {                       // X fp32 -> bf16 (4096x1024)
        const size_t idx = ((size_t)b * 256 + threadIdx.x) * 8;
        const float4 a = *reinterpret_cast<const float4*>(X + idx);
        const float4 c = *reinterpret_cast<const float4*>(X + idx + 4);
        short8 v;
        v[0] = f2bf(a.x); v[1] = f2bf(a.y); v[2] = f2bf(a.z); v[3] = f2bf(a.w);
        v[4] = f2bf(c.x); v[5] = f2bf(c.y); v[6] = f2bf(c.z); v[7] = f2bf(c.w);
        *reinterpret_cast<short8*>(Xb + idx) = v;
        return;
    }
    b -= 2048;
    if (b < 1024) { transpose_tile(hp,  WhpT, 1024, 1024,  1024,  b % 32,   b / 32);   return; }
    b -= 1024;
    if (b < 256)  { transpose_tile(t1p, W1pT, 1024, 256,   256,   b % 8,    b / 8);    return; }
    b -= 256;
    if (b < 64)   { transpose_tile(t2p, W2pT, 1024, 64,    64,    b % 2,    b / 2);    return; }
    b -= 64;
    if (b < 2048) { transpose_tile(hw,  WhT,  1024, 2002,  2048,  b % 64,   b / 64);   return; }
    b -= 2048;
    if (b < 2048) { transpose_tile(t1w, W1T,  256,  8000,  8192,  b % 256,  b / 256);  return; }
    b -= 2048;
    if (b < 2560) { transpose_tile(t2w, W2T,  64,  40000,  40960, b % 1280, b / 1280); return; }
    b -= 2560;
    if (b < 16) {   // compaction: 16 blocks x 256 threads = 4096 rows
        const int i = b * 256 + threadIdx.x;
        const int lab = labels[i];
        if (lab >= 2000 && lab < 10000) idx1[atomicAdd(&counts[0], 1)] = i;
        else if (lab >= 10000)          idx2[atomicAdd(&counts[1], 1)] = i;
        return;
    }
    b -= 16;
    {   // exp(bias) tables: [0,8000)->eb1, [8000,48000)->eb2t (188 blocks)
        const int i = b * 256 + threadIdx.x;
        if (i < 8000)       eb1[i] = __expf(t1b[i]);
        else if (i < 48000) eb2t[i - 8000] = __expf(t2b[i - 8000]);
    }
}

// ---- proj5: dbuf LDS A (static kh), B-stationary regs, gelu epilogue ------
// col space [0,1344): [0,1024)->H, [1024,1280)->T1, [1280,1344)->T2
__global__ __launch_bounds__(512, 2)
void proj5(const short* __restrict__ Xb,
           const short* __restrict__ WhpT, const short* __restrict__ W1pT,
           const short* __restrict__ W2pT,
           short* __restrict__ H, short* __restrict__ T1, short* __restrict__ T2)
{
    constexpr int KSTEP = 256, CHB = 32 * KSTEP * 2;   // 16 KB per buffer
    __shared__ char sA[2][CHB];
    const int tid = threadIdx.x, w = tid >> 6, l = tid & 63;
    const int arow = l & 15, kg = l >> 4;
    const int c_g = (blockIdx.y * 8 + w) * 16;
    const short* Bt; short* Pout; int Vout, cl; bool active = true;
    if (c_g < 1024)      { Bt = WhpT; Pout = H;  Vout = 1024; cl = c_g; }
    else if (c_g < 1280) { Bt = W1pT; Pout = T1; Vout = 256;  cl = c_g - 1024; }
    else if (c_g < 1344) { Bt = W2pT; Pout = T2; Vout = 64;   cl = c_g - 1280; }
    else                 { Bt = W2pT; Pout = T2; Vout = 64;   cl = 0; active = false; }

    short8 breg[32];                      // B stationary, 128 VGPR (static idx)
    const short* bp = Bt + (size_t)(cl + arow) * DIM + kg * 8;
    #pragma unroll
    for (int f = 0; f < 32; ++f) breg[f] = *reinterpret_cast<const short8*>(bp + f * 32);

    const int g0 = blockIdx.x * 128;
    short8 st8[2];
    auto load_chunk = [&](int rt, int kh) {
        #pragma unroll
        for (int j = 0; j < 2; ++j) {
            const int v = tid + j * 512;
            const int m = v >> 5, c8 = v & 31;
            st8[j] = *reinterpret_cast<const short8*>(
                Xb + (size_t)(g0 + rt * 32 + m) * DIM + kh * KSTEP + c8 * 8);
        }
    };
    auto store_chunk = [&](int buf) {
        char* base = &sA[buf][0];
        #pragma unroll
        for (int j = 0; j < 2; ++j) {
            const int v = tid + j * 512;
            const int m = v >> 5, c8 = v & 31;
            *reinterpret_cast<short8*>(
                base + (((m * KSTEP + c8 * 8) * 2) ^ ((m & 7) << 4))) = st8[j];
        }
    };

    load_chunk(0, 0); store_chunk(0); __syncthreads();
    f32x4 acc[2] = {(f32x4){0.f,0.f,0.f,0.f}, (f32x4){0.f,0.f,0.f,0.f}};
    for (int rt = 0; rt < 4; ++rt) {
        #pragma unroll
        for (int kh = 0; kh < 4; ++kh) {
            const int buf = kh & 1;                       // compile-time parity
            const bool last = (rt == 3) && (kh == 3);
            if (!last) load_chunk(kh < 3 ? rt : rt + 1, (kh + 1) & 3);
            const char* base = &sA[buf][0];
            #pragma unroll
            for (int f = 0; f < 8; ++f) {
                const short8 af0 = *reinterpret_cast<const short8*>(
                    base + (((arow * KSTEP + f * 32 + kg * 8) * 2) ^ ((arow & 7) << 4)));
                const short8 af1 = *reinterpret_cast<const short8*>(
                    base + ((((16 + arow) * KSTEP + f * 32 + kg * 8) * 2) ^ ((arow & 7) << 4)));
                acc[0] = __builtin_amdgcn_mfma_f32_16x16x32_bf16(af0, breg[kh * 8 + f], acc[0], 0, 0, 0);
                acc[1] = __builtin_amdgcn_mfma_f32_16x16x32_bf16(af1, breg[kh * 8 + f], acc[1], 0, 0, 0);
            }
            if (kh == 3) {
                if (active) {
                    #pragma unroll
                    for (int mr = 0; mr < 2; ++mr)
                        #pragma unroll
                        for (int r = 0; r < 4; ++r)
                            Pout[(size_t)(g0 + rt * 32 + mr * 16 + kg * 4 + r) * Vout + cl + arow] =
                                f2bf(gelu_exact(acc[mr][r]));
                }
                acc[0] = (f32x4){0.f,0.f,0.f,0.f};
                acc[1] = (f32x4){0.f,0.f,0.f,0.f};
            }
            if (!last) store_chunk(buf ^ 1);
            __syncthreads();
        }
    }
}

// ---- ce_core (head only): dbuf LDS A, B-stationary, __expf epilogue ------
template<int K, int NT, bool IDENT, int RPG>
__device__ __forceinline__
void ce_core(const short* __restrict__ A, const short* __restrict__ Bt,
             const float* __restrict__ bias, const int* __restrict__ rows,
             const int* __restrict__ countp, float* __restrict__ sum_acc,
             int V, int bx, int by,
             char* __restrict__ sA, float* __restrict__ lsum, int* __restrict__ rlds)
{
    constexpr int KSTEP = (K > 256) ? 256 : K;
    constexpr int NKH   = K / KSTEP;
    constexpr int NKFS  = KSTEP / 32;
    constexpr int NKF   = K / 32;
    constexpr int CHB   = 32 * KSTEP * 2;
    constexpr int NV8   = 32 * KSTEP / 8;
    constexpr int VPT   = (NV8 + 511) / 512;

    const int cnt = IDENT ? NTOK : *countp;
    const int g0 = bx * RPG;
    if (g0 >= cnt) return;
    const int ng = min(RPG, cnt - g0);
    const int tid = threadIdx.x;
    const int w = tid >> 6, l = tid & 63;
    const int arow = l & 15, kg = l >> 4;

    for (int t = tid; t < RPG; t += 512) {
        lsum[t] = 0.f;
        rlds[t] = IDENT ? (g0 + t) : rows[min(g0 + t, cnt - 1)];
    }

    int ct[NT]; float cb[NT]; short8 breg[NT][NKF];
    #pragma unroll
    for (int t = 0; t < NT; ++t) {
        ct[t] = (by * 8 + w) * (16 * NT) + t * 16;
        const int col = ct[t] + arow;
        cb[t] = (col < V) ? __expf(bias[col]) : 0.f;
        const short* bp = Bt + (size_t)(ct[t] + arow) * K + kg * 8;
        #pragma unroll
        for (int f = 0; f < NKF; ++f)
            breg[t][f] = *reinterpret_cast<const short8*>(bp + f * 32);
    }
    __syncthreads();

    const int NRT = (ng + 31) / 32;

    short8 st8[VPT];
    auto load_chunk = [&](int c) {
        const int rt = c / NKH, kh = c % NKH, rb = rt * 32;
        #pragma unroll
        for (int j = 0; j < VPT; ++j) {
            const int v = tid + j * 512;
            if (v < NV8) {
                const int m = v / (KSTEP / 8), c8 = v % (KSTEP / 8);
                st8[j] = *reinterpret_cast<const short8*>(
                    A + (size_t)rlds[min(rb + m, RPG - 1)] * K + kh * KSTEP + c8 * 8);
            }
        }
    };
    auto store_chunk = [&](int buf) {
        char* base = sA + buf * CHB;
        #pragma unroll
        for (int j = 0; j < VPT; ++j) {
            const int v = tid + j * 512;
            if (v < NV8) {
                const int m = v / (KSTEP / 8), c8 = v % (KSTEP / 8);
                *reinterpret_cast<short8*>(
                    base + (((m * KSTEP + c8 * 8) * 2) ^ ((m & 7) << 4))) = st8[j];
            }
        }
    };

    load_chunk(0); store_chunk(0); __syncthreads();

    f32x4 acc[2][NT];
    #pragma unroll
    for (int mr = 0; mr < 2; ++mr)
        #pragma unroll
        for (int t = 0; t < NT; ++t) acc[mr][t] = (f32x4){0.f,0.f,0.f,0.f};

    for (int rt = 0; rt < NRT; ++rt) {
        #pragma unroll
        for (int kh = 0; kh < NKH; ++kh) {
            const int c   = rt * NKH + kh;
            const int buf = (NKH > 1) ? (kh & 1) : (rt & 1);
            const bool last = (c + 1 == NRT * NKH);
            if (!last) load_chunk(c + 1);
            const char* base = sA + buf * CHB;
            #pragma unroll
            for (int f = 0; f < NKFS; ++f) {
                const short8 af0 = *reinterpret_cast<const short8*>(
                    base + (((arow * KSTEP + f * 32 + kg * 8) * 2) ^ ((arow & 7) << 4)));
                const short8 af1 = *reinterpret_cast<const short8*>(
                    base + ((((16 + arow) * KSTEP + f * 32 + kg * 8) * 2) ^ ((arow & 7) << 4)));
                #pragma unroll
                for (int t = 0; t < NT; ++t) {
                    acc[0][t] = __builtin_amdgcn_mfma_f32_16x16x32_bf16(
                        af0, breg[t][kh * NKFS + f], acc[0][t], 0, 0, 0);
                    acc[1][t] = __builtin_amdgcn_mfma_f32_16x16x32_bf16(
                        af1, breg[t][kh * NKFS + f], acc[1][t], 0, 0, 0);
                }
            }
            if (kh == NKH - 1) {
                const int rb = rt * 32;
                #pragma unroll
                for (int mr = 0; mr < 2; ++mr) {
                    float sacc[4] = {0.f, 0.f, 0.f, 0.f};
                    #pragma unroll
                    for (int t = 0; t < NT; ++t)
                        #pragma unroll
                        for (int r = 0; r < 4; ++r)
                            sacc[r] = fmaf(__expf(acc[mr][t][r]), cb[t], sacc[r]);
                    #pragma unroll
                    for (int r = 0; r < 4; ++r) {
                        float v = sacc[r];
                        v += __shfl_xor(v, 1); v += __shfl_xor(v, 2);
                        v += __shfl_xor(v, 4); v += __shfl_xor(v, 8);
                        if (arow == 0) atomicAdd(&lsum[rb + mr * 16 + kg * 4 + r], v);
                    }
                    #pragma unroll
                    for (int t = 0; t < NT; ++t) acc[mr][t] = (f32x4){0.f,0.f,0.f,0.f};
                }
            }
            if (!last) store_chunk(buf ^ 1);
            __syncthreads();
        }
    }
    for (int t = tid; t < ng; t += 512)
        atomicAdd(&sum_acc[rlds[t]], lsum[t]);
}

__global__ __launch_bounds__(512, 2)
void ce_head(const short* __restrict__ H, const short* __restrict__ WhT,
             const float* __restrict__ head_b, float* __restrict__ hsum)
{
    __shared__ char  sA[2][16384];
    __shared__ float lsum[128];
    __shared__ int   rlds[128];
    ce_core<1024, 1, true, 128>(H, WhT, head_b, nullptr, nullptr, hsum, 2002,
                                blockIdx.x, blockIdx.y, &sA[0][0], lsum, rlds);
}

// ---- ce_swap: operand-swapped CE (tokens stationary, W streamed) ---------
// C col = lane&15 = token -> sum-of-exp accumulates IN-LANE. No LDS, no
// barriers, no per-tile shuffles. One 2-shuffle reduce + 1 atomic/token.
template<int NKF, bool IDENT>
__device__ __forceinline__
void ce_swap_core(const short* __restrict__ P, const short* __restrict__ Wt,
                  const float* __restrict__ eb, const int* __restrict__ rows,
                  const int* __restrict__ countp, float* __restrict__ sum_acc,
                  int ntiles, int tps, int tg, int split)
{
    constexpr int K = NKF * 32;
    const int cnt = IDENT ? NTOK : *countp;
    const int g0 = tg * 128;
    if (g0 >= cnt) return;                 // uniform exit
    const int l = threadIdx.x & 63, w = threadIdx.x >> 6;
    const int n = l & 15, kg = l >> 4;
    const int j = g0 + w * 16 + n;
    const bool valid = j < cnt;
    const int tok = IDENT ? min(j, NTOK - 1) : rows[min(j, cnt - 1)];

    short8 bf[NKF];                        // stationary token fragments
    {
        const short* xp = P + (size_t)tok * K + kg * 8;
        #pragma unroll
        for (int f = 0; f < NKF; ++f)
            bf[f] = *reinterpret_cast<const short8*>(xp + f * 32);
    }

    const int t0 = split * tps, t1e = min(ntiles, t0 + tps);
    const short* wbase = Wt + (size_t)n * K + kg * 8;
    const float* ebase = eb + kg * 4;
    float s0 = 0.f, s1 = 0.f;
    for (int t = t0; t < t1e; ++t) {
        const short* wp = wbase + (size_t)t * 16 * K;
        f32x4 acc = {0.f, 0.f, 0.f, 0.f};
        #pragma unroll
        for (int f = 0; f < NKF; ++f)
            acc = __builtin_amdgcn_mfma_f32_16x16x32_bf16(
                *reinterpret_cast<const short8*>(wp + f * 32), bf[f], acc, 0, 0, 0);
        const float4 e4 = *reinterpret_cast<const float4*>(ebase + t * 16);
        s0 = fmaf(__expf(acc[0]), e4.x, s0);
        s1 = fmaf(__expf(acc[1]), e4.y, s1);
        s0 = fmaf(__expf(acc[2]), e4.z, s0);
        s1 = fmaf(__expf(acc[3]), e4.w, s1);
    }
    float s = s0 + s1;
    s += __shfl_xor(s, 16);
    s += __shfl_xor(s, 32);
    if (kg == 0 && valid) atomicAdd(&sum_acc[tok], s);
}

#define NBT2 1280   // 32 token-groups x 40 col-splits
__global__ __launch_bounds__(512, 4)
void ce_tails_swap(const short* __restrict__ T1, const short* __restrict__ W1T,
                   const float* __restrict__ eb1,
                   const short* __restrict__ T2, const short* __restrict__ W2T,
                   const float* __restrict__ eb2t,
                   const int* __restrict__ idx1, const int* __restrict__ idx2,
                   const int* __restrict__ counts, float* __restrict__ tsum)
{
    const int b = blockIdx.x;
    if (b < NBT2) {
        // t2: K=64, 2500 tiles, 40 splits of 63
        ce_swap_core<2, false>(T2, W2T, eb2t, idx2, &counts[1], tsum,
                               2500, 63, b & 31, b >> 5);
    } else {
        // t1: K=256, 500 tiles, 24 splits of 21
        const int b2 = b - NBT2;
        ce_swap_core<8, false>(T1, W1T, eb1, idx1, &counts[0], tsum,
                               500, 21, b2 & 31, b2 >> 5);
    }
}

// ---- finalize: recompute label logits (tiny dots) + assemble loss --------
__global__ __launch_bounds__(256)
void finalize_kernel(const int* __restrict__ labels,
                     const short* __restrict__ H,  const short* __restrict__ WhT,
                     const float* __restrict__ head_b,
                     const short* __restrict__ T1, const short* __restrict__ W1T,
                     const float* __restrict__ t1b,
                     const short* __restrict__ T2, const short* __restrict__ W2T,
                     const float* __restrict__ t2b,
                     const float* __restrict__ hsum, const float* __restrict__ tsum,
                     float* __restrict__ out)
{
    const int r = blockIdx.x * 4 + (threadIdx.x >> 6);   // one wave per row
    const int l = threadIdx.x & 63;
    if (r >= NTOK) return;
    const int lab = labels[r];
    int labH = lab;
    if (lab >= 10000) labH = 2001; else if (lab >= 2000) labH = 2000;

    float d = 0.f;                                       // head label dot, K=1024
    {
        const short* a = H   + (size_t)r    * 1024 + l * 16;
        const short* b = WhT + (size_t)labH * 1024 + l * 16;
        #pragma unroll
        for (int u = 0; u < 2; ++u) {
            const short8 av = *reinterpret_cast<const short8*>(a + u * 8);
            const short8 bv = *reinterpret_cast<const short8*>(b + u * 8);
            #pragma unroll
            for (int e = 0; e < 8; ++e) d = fmaf(bf2f(av[e]), bf2f(bv[e]), d);
        }
    }
    float td = 0.f;                                      // tail label dot
    if (lab >= 2000) {
        const short* a; const short* b; int nl;
        if (lab < 10000) { a = T1 + (size_t)r * 256; b = W1T + (size_t)(lab - 2000) * 256; nl = 32; }
        else             { a = T2 + (size_t)r * 64;  b = W2T + (size_t)(lab - 10000) * 64; nl = 8; }
        if (l < nl) {
            const short8 av = *reinterpret_cast<const short8*>(a + l * 8);
            const short8 bv = *reinterpret_cast<const short8*>(b + l * 8);
            #pragma unroll
            for (int e = 0; e < 8; ++e) td = fmaf(bf2f(av[e]), bf2f(bv[e]), td);
        }
    }
    #pragma unroll
    for (int off = 32; off; off >>= 1) { d += __shfl_xor(d, off); td += __shfl_xor(td, off); }
    if (l == 0) {
        float loss = logf(hsum[r]) - (d + head_b[labH]);
        if (lab >= 2000) {
            const float tb = (lab < 10000) ? t1b[lab - 2000] : t2b[lab - 10000];
            loss += logf(tsum[r]) - (td + tb);
        }
        out[r] = loss;
    }
}

extern "C" void kernel_launch(void* const* d_in, const int* in_sizes, int n_in,
                              void* d_out, int out_size, void* d_ws, size_t ws_size,
                              hipStream_t stream) {
    (void)in_sizes; (void)n_in; (void)out_size; (void)ws_size;
    const float* X         = (const float*)d_in[0];
    const int*   labels    = (const int*)  d_in[1];
    const float* head_proj = (const float*)d_in[2];
    const float* head_w    = (const float*)d_in[3];
    const float* head_b    = (const float*)d_in[4];
    const float* t1p       = (const float*)d_in[5];
    const float* t1w       = (const float*)d_in[6];
    const float* t1b       = (const float*)d_in[7];
    const float* t2p       = (const float*)d_in[8];
    const float* t2w       = (const float*)d_in[9];
    const float* t2b       = (const float*)d_in[10];
    float* out = (float*)d_out;

    char* ws = (char*)d_ws;
    int*   counts = (int*)ws;                      // 2 ints
    int*   idx1   = (int*)(ws + 1024);
    int*   idx2   = (int*)(ws + 1024 + 16384);
    float* hsum   = (float*)(ws + 65536);          // 2 x 4096 f32
    float* tsum   = hsum + NTOK;

    short* p = (short*)(ws + 131072);
    short* Xb   = p; p += (size_t)NTOK * 1024;
    short* WhpT = p; p += (size_t)1024 * 1024;
    short* W1pT = p; p += (size_t)256  * 1024;
    short* W2pT = p; p += (size_t)64   * 1024;
    short* WhT  = p; p += (size_t)2048 * 1024;     // pad 2002->2048
    short* W1T  = p; p += (size_t)8192 * 256;      // pad 8000->8192
    short* W2T  = p; p += (size_t)40960 * 64;      // pad 40000->40960
    short* H    = p; p += (size_t)NTOK * 1024;
    short* T1   = p; p += (size_t)NTOK * 256;
    short* T2   = p; p += (size_t)NTOK * 64;
    float* eb1  = (float*)p; p += 2 * 8000;        // exp(t1b), 8000 f32
    float* eb2t = (float*)p; p += 2 * 40000;       // exp(t2b), 40000 f32

    hipMemsetAsync(counts, 0, 16, stream);
    hipMemsetAsync(hsum, 0, 2 * NTOK * sizeof(float), stream);

    prep_kernel<<<10252, 256, 0, stream>>>(X, Xb, head_proj, WhpT, t1p, W1pT,
                                           t2p, W2pT, head_w, WhT, t1w, W1T, t2w, W2T,
                                           labels, idx1, idx2, counts,
                                           t1b, t2b, eb1, eb2t);
    // proj: 1344 cols -> 11 col-groups of 128; 32 row-groups of 128
    proj5<<<dim3(32, 11), 512, 0, stream>>>(Xb, WhpT, W1pT, W2pT, H, T1, T2);

    // head: V=2002 (2048 -> 16 col-groups of 128), K=1024, RPG=128
    ce_head<<<dim3(32, 16), 512, 0, stream>>>(H, WhT, head_b, hsum);
    // tails, operand-swapped: t2 (32 tg x 40 splits) + t1 (32 tg x 24 splits)
    ce_tails_swap<<<NBT2 + 768, 512, 0, stream>>>(T1, W1T, eb1, T2, W2T, eb2t,
                                                  idx1, idx2, counts, tsum);

    finalize_kernel<<<NTOK / 4, 256, 0, stream>>>(
        labels, H, WhT, head_b, T1, W1T, t1b, T2, W2T, t2b, hsum, tsum, out);
}

// Round 13
// 191.965 us; speedup vs baseline: 2.2295x; 2.2295x over previous
//
#include <hip/hip_runtime.h>
#include <hip/hip_bf16.h>
#include <math.h>

#define NTOK 4096
#define DIM  1024

typedef __attribute__((ext_vector_type(8))) short short8;   // 8 bf16 = 4 VGPR
typedef __attribute__((ext_vector_type(4))) float f32x4;

__device__ __forceinline__ short f2bf(float f) {
    return __builtin_bit_cast(short, __float2bfloat16(f));
}
__device__ __forceinline__ float bf2f(short s) {
    unsigned u = ((unsigned)(unsigned short)s) << 16;
    return __builtin_bit_cast(float, u);
}
__device__ __forceinline__ float gelu_exact(float x) {
    return x * 0.5f * (1.0f + erff(x * 0.70710678118654752f));
}

// ------- fused prep: X->bf16 + 6 weight transposes + compaction -----------
__device__ __forceinline__
void transpose_tile(const float* __restrict__ src, short* __restrict__ dst,
                    int K, int V, int Vpad, int vt, int kt)
{
    __shared__ float tile[32][33];
    const int v0 = vt * 32, k0 = kt * 32;
    const int tx = threadIdx.x & 31, ty = threadIdx.x >> 5;   // 32 x 8
    #pragma unroll
    for (int i = 0; i < 4; ++i) {
        const int k = k0 + ty + 8 * i, v = v0 + tx;
        tile[ty + 8 * i][tx] = (k < K && v < V) ? src[(size_t)k * V + v] : 0.f;
    }
    __syncthreads();
    #pragma unroll
    for (int i = 0; i < 4; ++i) {
        const int v = v0 + ty + 8 * i, k = k0 + tx;
        if (v < Vpad && k < K) dst[(size_t)v * K + k] = f2bf(tile[tx][ty + 8 * i]);
    }
}

__global__ __launch_bounds__(256)
void prep_kernel(const float* __restrict__ X, short* __restrict__ Xb,
                 const float* __restrict__ hp,  short* __restrict__ WhpT,
                 const float* __restrict__ t1p, short* __restrict__ W1pT,
                 const float* __restrict__ t2p, short* __restrict__ W2pT,
                 const float* __restrict__ hw,  short* __restrict__ WhT,
                 const float* __restrict__ t1w, short* __restrict__ W1T,
                 const float* __restrict__ t2w, short* __restrict__ W2T,
                 const int* __restrict__ labels,
                 int* __restrict__ idx1, int* __restrict__ idx2,
                 int* __restrict__ counts)
{
    int b = blockIdx.x;
    if (b < 2048) {                       // X fp32 -> bf16 (4096x1024)
        const size_t idx = ((size_t)b * 256 + threadIdx.x) * 8;
        const float4 a = *reinterpret_cast<const float4*>(X + idx);
        const float4 c = *reinterpret_cast<const float4*>(X + idx + 4);
        short8 v;
        v[0] = f2bf(a.x); v[1] = f2bf(a.y); v[2] = f2bf(a.z); v[3] = f2bf(a.w);
        v[4] = f2bf(c.x); v[5] = f2bf(c.y); v[6] = f2bf(c.z); v[7] = f2bf(c.w);
        *reinterpret_cast<short8*>(Xb + idx) = v;
        return;
    }
    b -= 2048;
    if (b < 1024) { transpose_tile(hp,  WhpT, 1024, 1024,  1024,  b % 32,   b / 32);   return; }
    b -= 1024;
    if (b < 256)  { transpose_tile(t1p, W1pT, 1024, 256,   256,   b % 8,    b / 8);    return; }
    b -= 256;
    if (b < 64)   { transpose_tile(t2p, W2pT, 1024, 64,    64,    b % 2,    b / 2);    return; }
    b -= 64;
    if (b < 2048) { transpose_tile(hw,  WhT,  1024, 2002,  2048,  b % 64,   b / 64);   return; }
    b -= 2048;
    if (b < 2048) { transpose_tile(t1w, W1T,  256,  8000,  8192,  b % 256,  b / 256);  return; }
    b -= 2048;
    if (b < 2560) { transpose_tile(t2w, W2T,  64,  40000,  40960, b % 1280, b / 1280); return; }
    b -= 2560;
    {   // compaction: 16 blocks x 256 threads = 4096 rows
        const int i = b * 256 + threadIdx.x;
        const int lab = labels[i];
        if (lab >= 2000 && lab < 10000) idx1[atomicAdd(&counts[0], 1)] = i;
        else if (lab >= 10000)          idx2[atomicAdd(&counts[1], 1)] = i;
    }
}

// ---- proj5: dbuf LDS A (static kh), B-stationary regs, gelu epilogue ------
__global__ __launch_bounds__(512, 2)
void proj5(const short* __restrict__ Xb,
           const short* __restrict__ WhpT, const short* __restrict__ W1pT,
           const short* __restrict__ W2pT,
           short* __restrict__ H, short* __restrict__ T1, short* __restrict__ T2)
{
    constexpr int KSTEP = 256, CHB = 32 * KSTEP * 2;   // 16 KB per buffer
    __shared__ char sA[2][CHB];
    const int tid = threadIdx.x, w = tid >> 6, l = tid & 63;
    const int arow = l & 15, kg = l >> 4;
    const int c_g = (blockIdx.y * 8 + w) * 16;
    const short* Bt; short* Pout; int Vout, cl; bool active = true;
    if (c_g < 1024)      { Bt = WhpT; Pout = H;  Vout = 1024; cl = c_g; }
    else if (c_g < 1280) { Bt = W1pT; Pout = T1; Vout = 256;  cl = c_g - 1024; }
    else if (c_g < 1344) { Bt = W2pT; Pout = T2; Vout = 64;   cl = c_g - 1280; }
    else                 { Bt = W2pT; Pout = T2; Vout = 64;   cl = 0; active = false; }

    short8 breg[32];                      // B stationary, 128 VGPR (static idx)
    const short* bp = Bt + (size_t)(cl + arow) * DIM + kg * 8;
    #pragma unroll
    for (int f = 0; f < 32; ++f) breg[f] = *reinterpret_cast<const short8*>(bp + f * 32);

    const int g0 = blockIdx.x * 128;
    short8 st8[2];
    auto load_chunk = [&](int rt, int kh) {
        #pragma unroll
        for (int j = 0; j < 2; ++j) {
            const int v = tid + j * 512;
            const int m = v >> 5, c8 = v & 31;
            st8[j] = *reinterpret_cast<const short8*>(
                Xb + (size_t)(g0 + rt * 32 + m) * DIM + kh * KSTEP + c8 * 8);
        }
    };
    auto store_chunk = [&](int buf) {
        char* base = &sA[buf][0];
        #pragma unroll
        for (int j = 0; j < 2; ++j) {
            const int v = tid + j * 512;
            const int m = v >> 5, c8 = v & 31;
            *reinterpret_cast<short8*>(
                base + (((m * KSTEP + c8 * 8) * 2) ^ ((m & 7) << 4))) = st8[j];
        }
    };

    load_chunk(0, 0); store_chunk(0); __syncthreads();
    f32x4 acc[2] = {(f32x4){0.f,0.f,0.f,0.f}, (f32x4){0.f,0.f,0.f,0.f}};
    for (int rt = 0; rt < 4; ++rt) {
        #pragma unroll
        for (int kh = 0; kh < 4; ++kh) {
            const int buf = kh & 1;                       // compile-time parity
            const bool last = (rt == 3) && (kh == 3);
            if (!last) load_chunk(kh < 3 ? rt : rt + 1, (kh + 1) & 3);
            const char* base = &sA[buf][0];
            #pragma unroll
            for (int f = 0; f < 8; ++f) {
                const short8 af0 = *reinterpret_cast<const short8*>(
                    base + (((arow * KSTEP + f * 32 + kg * 8) * 2) ^ ((arow & 7) << 4)));
                const short8 af1 = *reinterpret_cast<const short8*>(
                    base + ((((16 + arow) * KSTEP + f * 32 + kg * 8) * 2) ^ ((arow & 7) << 4)));
                acc[0] = __builtin_amdgcn_mfma_f32_16x16x32_bf16(af0, breg[kh * 8 + f], acc[0], 0, 0, 0);
                acc[1] = __builtin_amdgcn_mfma_f32_16x16x32_bf16(af1, breg[kh * 8 + f], acc[1], 0, 0, 0);
            }
            if (kh == 3) {
                if (active) {
                    #pragma unroll
                    for (int mr = 0; mr < 2; ++mr)
                        #pragma unroll
                        for (int r = 0; r < 4; ++r)
                            Pout[(size_t)(g0 + rt * 32 + mr * 16 + kg * 4 + r) * Vout + cl + arow] =
                                f2bf(gelu_exact(acc[mr][r]));
                }
                acc[0] = (f32x4){0.f,0.f,0.f,0.f};
                acc[1] = (f32x4){0.f,0.f,0.f,0.f};
            }
            if (!last) store_chunk(buf ^ 1);
            __syncthreads();
        }
    }
}

// ---- ce_core (t1): dbuf LDS A, B-stationary regs, __expf epilogue --------
template<int K, int NT, bool IDENT, int RPG>
__device__ __forceinline__
void ce_core(const short* __restrict__ A, const short* __restrict__ Bt,
             const float* __restrict__ bias, const int* __restrict__ rows,
             const int* __restrict__ countp, float* __restrict__ sum_acc,
             int V, int bx, int by,
             char* __restrict__ sA, float* __restrict__ lsum, int* __restrict__ rlds)
{
    constexpr int KSTEP = (K > 256) ? 256 : K;
    constexpr int NKH   = K / KSTEP;
    constexpr int NKFS  = KSTEP / 32;
    constexpr int NKF   = K / 32;
    constexpr int CHB   = 32 * KSTEP * 2;
    constexpr int NV8   = 32 * KSTEP / 8;
    constexpr int VPT   = (NV8 + 511) / 512;

    const int cnt = IDENT ? NTOK : *countp;
    const int g0 = bx * RPG;
    if (g0 >= cnt) return;
    const int ng = min(RPG, cnt - g0);
    const int tid = threadIdx.x;
    const int w = tid >> 6, l = tid & 63;
    const int arow = l & 15, kg = l >> 4;

    for (int t = tid; t < RPG; t += 512) {
        lsum[t] = 0.f;
        rlds[t] = IDENT ? (g0 + t) : rows[min(g0 + t, cnt - 1)];
    }

    int ct[NT]; float cb[NT]; short8 breg[NT][NKF];
    #pragma unroll
    for (int t = 0; t < NT; ++t) {
        ct[t] = (by * 8 + w) * (16 * NT) + t * 16;
        const int col = ct[t] + arow;
        cb[t] = (col < V) ? __expf(bias[col]) : 0.f;
        const short* bp = Bt + (size_t)(ct[t] + arow) * K + kg * 8;
        #pragma unroll
        for (int f = 0; f < NKF; ++f)
            breg[t][f] = *reinterpret_cast<const short8*>(bp + f * 32);
    }
    __syncthreads();

    const int NRT = (ng + 31) / 32;

    short8 st8[VPT];
    auto load_chunk = [&](int c) {
        const int rt = c / NKH, kh = c % NKH, rb = rt * 32;
        #pragma unroll
        for (int j = 0; j < VPT; ++j) {
            const int v = tid + j * 512;
            if (v < NV8) {
                const int m = v / (KSTEP / 8), c8 = v % (KSTEP / 8);
                st8[j] = *reinterpret_cast<const short8*>(
                    A + (size_t)rlds[min(rb + m, RPG - 1)] * K + kh * KSTEP + c8 * 8);
            }
        }
    };
    auto store_chunk = [&](int buf) {
        char* base = sA + buf * CHB;
        #pragma unroll
        for (int j = 0; j < VPT; ++j) {
            const int v = tid + j * 512;
            if (v < NV8) {
                const int m = v / (KSTEP / 8), c8 = v % (KSTEP / 8);
                *reinterpret_cast<short8*>(
                    base + (((m * KSTEP + c8 * 8) * 2) ^ ((m & 7) << 4))) = st8[j];
            }
        }
    };

    load_chunk(0); store_chunk(0); __syncthreads();

    f32x4 acc[2][NT];
    #pragma unroll
    for (int mr = 0; mr < 2; ++mr)
        #pragma unroll
        for (int t = 0; t < NT; ++t) acc[mr][t] = (f32x4){0.f,0.f,0.f,0.f};

    for (int rt = 0; rt < NRT; ++rt) {
        #pragma unroll
        for (int kh = 0; kh < NKH; ++kh) {
            const int c   = rt * NKH + kh;
            const int buf = (NKH > 1) ? (kh & 1) : (rt & 1);
            const bool last = (c + 1 == NRT * NKH);
            if (!last) load_chunk(c + 1);
            const char* base = sA + buf * CHB;
            #pragma unroll
            for (int f = 0; f < NKFS; ++f) {
                const short8 af0 = *reinterpret_cast<const short8*>(
                    base + (((arow * KSTEP + f * 32 + kg * 8) * 2) ^ ((arow & 7) << 4)));
                const short8 af1 = *reinterpret_cast<const short8*>(
                    base + ((((16 + arow) * KSTEP + f * 32 + kg * 8) * 2) ^ ((arow & 7) << 4)));
                #pragma unroll
                for (int t = 0; t < NT; ++t) {
                    acc[0][t] = __builtin_amdgcn_mfma_f32_16x16x32_bf16(
                        af0, breg[t][kh * NKFS + f], acc[0][t], 0, 0, 0);
                    acc[1][t] = __builtin_amdgcn_mfma_f32_16x16x32_bf16(
                        af1, breg[t][kh * NKFS + f], acc[1][t], 0, 0, 0);
                }
            }
            if (kh == NKH - 1) {
                const int rb = rt * 32;
                #pragma unroll
                for (int mr = 0; mr < 2; ++mr) {
                    float sacc[4] = {0.f, 0.f, 0.f, 0.f};
                    #pragma unroll
                    for (int t = 0; t < NT; ++t)
                        #pragma unroll
                        for (int r = 0; r < 4; ++r)
                            sacc[r] = fmaf(__expf(acc[mr][t][r]), cb[t], sacc[r]);
                    #pragma unroll
                    for (int r = 0; r < 4; ++r) {
                        float v = sacc[r];
                        v += __shfl_xor(v, 1); v += __shfl_xor(v, 2);
                        v += __shfl_xor(v, 4); v += __shfl_xor(v, 8);
                        if (arow == 0) atomicAdd(&lsum[rb + mr * 16 + kg * 4 + r], v);
                    }
                    #pragma unroll
                    for (int t = 0; t < NT; ++t) acc[mr][t] = (f32x4){0.f,0.f,0.f,0.f};
                }
            }
            if (!last) store_chunk(buf ^ 1);
            __syncthreads();
        }
    }
    for (int t = tid; t < ng; t += 512)
        atomicAdd(&sum_acc[rlds[t]], lsum[t]);
}

// ---- ce_head2: K=1024, dbuf LDS A + dbuf REGISTER B-chunks (low VGPR) ----
__device__ __forceinline__
void ce_head2(const short* __restrict__ A, const short* __restrict__ Bt,
              const float* __restrict__ bias, float* __restrict__ sum_acc,
              int bx, int by, char* __restrict__ sA, float* __restrict__ lsum)
{
    constexpr int K = 1024, KSTEP = 256, NKFS = 8;
    constexpr int CHB = 32 * KSTEP * 2;      // 16 KB per buffer
    const int tid = threadIdx.x, w = tid >> 6, l = tid & 63;
    const int arow = l & 15, kg = l >> 4;
    const int g0 = bx * 128;

    for (int t = tid; t < 128; t += 512) lsum[t] = 0.f;

    const int ct  = (by * 8 + w) * 16;       // wave's 16-col tile (<2048 always)
    const int col = ct + arow;
    const float cb = (col < 2002) ? __expf(bias[col]) : 0.f;
    const short* bbase = Bt + (size_t)col * K + kg * 8;

    short8 b0[NKFS], b1[NKFS];               // dbuf B chunks: 64 VGPR total
    #pragma unroll
    for (int f = 0; f < NKFS; ++f)
        b0[f] = *reinterpret_cast<const short8*>(bbase + f * 32);

    short8 st8[2];
    auto load_chunk = [&](int c) {           // A chunk c = rt*4+kh
        const int rt = c >> 2, kh = c & 3;
        #pragma unroll
        for (int j = 0; j < 2; ++j) {
            const int v = tid + j * 512;
            const int m = v >> 5, c8 = v & 31;
            st8[j] = *reinterpret_cast<const short8*>(
                A + (size_t)(g0 + rt * 32 + m) * K + kh * KSTEP + c8 * 8);
        }
    };
    auto store_chunk = [&](int buf) {
        char* base = sA + buf * CHB;
        #pragma unroll
        for (int j = 0; j < 2; ++j) {
            const int v = tid + j * 512;
            const int m = v >> 5, c8 = v & 31;
            *reinterpret_cast<short8*>(
                base + (((m * KSTEP + c8 * 8) * 2) ^ ((m & 7) << 4))) = st8[j];
        }
    };
    auto do_chunk = [&](const short8 (&bc)[NKFS], short8 (&bn)[NKFS],
                        int rt, int kh, f32x4& a0, f32x4& a1) {
        const int c = rt * 4 + kh;
        const bool last = (c == 15);
        if (!last) {
            load_chunk(c + 1);               // A prefetch (global)
            const int nkh = (kh + 1) & 3;    // B prefetch (L2-hot, same addrs/rt)
            #pragma unroll
            for (int f = 0; f < NKFS; ++f)
                bn[f] = *reinterpret_cast<const short8*>(bbase + nkh * KSTEP + f * 32);
        }
        const char* base = sA + (kh & 1) * CHB;
        #pragma unroll
        for (int f = 0; f < NKFS; ++f) {
            const short8 af0 = *reinterpret_cast<const short8*>(
                base + (((arow * KSTEP + f * 32 + kg * 8) * 2) ^ ((arow & 7) << 4)));
            const short8 af1 = *reinterpret_cast<const short8*>(
                base + ((((16 + arow) * KSTEP + f * 32 + kg * 8) * 2) ^ ((arow & 7) << 4)));
            a0 = __builtin_amdgcn_mfma_f32_16x16x32_bf16(af0, bc[f], a0, 0, 0, 0);
            a1 = __builtin_amdgcn_mfma_f32_16x16x32_bf16(af1, bc[f], a1, 0, 0, 0);
        }
        if (kh == 3) {                       // row-tile complete: exp epilogue
            const int rb = rt * 32;
            #pragma unroll
            for (int mr = 0; mr < 2; ++mr) {
                f32x4& aa = (mr == 0) ? a0 : a1;
                float sacc[4];
                #pragma unroll
                for (int r = 0; r < 4; ++r) sacc[r] = __expf(aa[r]) * cb;
                #pragma unroll
                for (int r = 0; r < 4; ++r) {
                    float v = sacc[r];
                    v += __shfl_xor(v, 1); v += __shfl_xor(v, 2);
                    v += __shfl_xor(v, 4); v += __shfl_xor(v, 8);
                    if (arow == 0) atomicAdd(&lsum[rb + mr * 16 + kg * 4 + r], v);
                }
            }
            a0 = (f32x4){0.f,0.f,0.f,0.f};
            a1 = (f32x4){0.f,0.f,0.f,0.f};
        }
        if (!last) store_chunk((kh & 1) ^ 1);
        __syncthreads();
    };

    load_chunk(0); store_chunk(0); __syncthreads();
    f32x4 a0 = {0.f,0.f,0.f,0.f}, a1 = {0.f,0.f,0.f,0.f};
    for (int rt = 0; rt < 4; ++rt) {
        do_chunk(b0, b1, rt, 0, a0, a1);     // kh parity -> static buffer names
        do_chunk(b1, b0, rt, 1, a0, a1);
        do_chunk(b0, b1, rt, 2, a0, a1);
        do_chunk(b1, b0, rt, 3, a0, a1);
    }
    for (int t = tid; t < 128; t += 512)
        atomicAdd(&sum_acc[g0 + t], lsum[t]);
}

// ---- t2 register path: K=64, barrier-free 8-tile ping-pong row loop ------
__device__ __forceinline__
void ce_reg64(const short* __restrict__ A, const short* __restrict__ Bt,
              const float* __restrict__ bias, const int* __restrict__ rows,
              const int* __restrict__ countp, float* __restrict__ sum_acc,
              int V, int bx, int by,
              float* __restrict__ lsum, int* __restrict__ rlds)
{
    constexpr int NT = 4, RPG = 256;
    const int cnt = *countp;
    const int g0 = bx * RPG;
    if (g0 >= cnt) return;
    const int ng = min(RPG, cnt - g0);
    const int tid = threadIdx.x;
    const int w = tid >> 6, l = tid & 63;
    const int arow = l & 15, kg = l >> 4;

    for (int t = tid; t < RPG; t += 512) {
        lsum[t] = 0.f;
        rlds[t] = rows[min(g0 + t, cnt - 1)];
    }

    int ct[NT]; float cb[NT]; short8 breg[NT][2];
    #pragma unroll
    for (int t = 0; t < NT; ++t) {
        ct[t] = (by * 8 + w) * 64 + t * 16;
        const int col = ct[t] + arow;
        cb[t] = (col < V) ? __expf(bias[col]) : 0.f;
        const short* bp = Bt + (size_t)(ct[t] + arow) * 64 + kg * 8;
        breg[t][0] = *reinterpret_cast<const short8*>(bp);
        breg[t][1] = *reinterpret_cast<const short8*>(bp + 32);
    }
    __syncthreads();                       // lsum/rlds ready

    auto load_tile = [&](int rt, short8 (&dst)[2][2]) {
        #pragma unroll
        for (int mr = 0; mr < 2; ++mr) {
            const int r = rlds[rt * 32 + mr * 16 + arow];
            const short* ap = A + (size_t)r * 64 + kg * 8;
            dst[mr][0] = *reinterpret_cast<const short8*>(ap);
            dst[mr][1] = *reinterpret_cast<const short8*>(ap + 32);
        }
    };
    auto compute_tile = [&](int rt, const short8 (&Ar)[2][2]) {
        f32x4 acc[2][NT];
        #pragma unroll
        for (int mr = 0; mr < 2; ++mr)
            #pragma unroll
            for (int t = 0; t < NT; ++t) acc[mr][t] = (f32x4){0.f,0.f,0.f,0.f};
        #pragma unroll
        for (int f = 0; f < 2; ++f)
            #pragma unroll
            for (int mr = 0; mr < 2; ++mr)
                #pragma unroll
                for (int t = 0; t < NT; ++t)
                    acc[mr][t] = __builtin_amdgcn_mfma_f32_16x16x32_bf16(
                        Ar[mr][f], breg[t][f], acc[mr][t], 0, 0, 0);
        const int rb = rt * 32;
        #pragma unroll
        for (int mr = 0; mr < 2; ++mr) {
            float sacc[4] = {0.f, 0.f, 0.f, 0.f};
            #pragma unroll
            for (int t = 0; t < NT; ++t)
                #pragma unroll
                for (int r = 0; r < 4; ++r)
                    sacc[r] = fmaf(__expf(acc[mr][t][r]), cb[t], sacc[r]);
            #pragma unroll
            for (int r = 0; r < 4; ++r) {
                float v = sacc[r];
                v += __shfl_xor(v, 1); v += __shfl_xor(v, 2);
                v += __shfl_xor(v, 4); v += __shfl_xor(v, 8);
                if (arow == 0) atomicAdd(&lsum[rb + mr * 16 + kg * 4 + r], v);
            }
        }
    };

    short8 A0[2][2], A1[2][2];
    load_tile(0, A0);
    load_tile(1, A1);
    #pragma unroll
    for (int rt = 0; rt < 8; rt += 2) {    // barrier-free, 1-tile-ahead pipeline
        compute_tile(rt, A0);
        if (rt + 2 < 8) load_tile(rt + 2, A0);
        compute_tile(rt + 1, A1);
        if (rt + 3 < 8) load_tile(rt + 3, A1);
    }

    __syncthreads();
    for (int t = tid; t < ng; t += 512)
        atomicAdd(&sum_acc[rlds[t]], lsum[t]);
}

// ---- fused CE: t2 [0,1280) + head [1280,1792) + t1 [1792,2048) -----------
// All range offsets % 8 == 0 -> XCD pinning preserved per path.
__global__ __launch_bounds__(512, 4)
void ce_fused(const short* __restrict__ H,  const short* __restrict__ WhT,
              const float* __restrict__ head_b, float* __restrict__ hsum,
              const short* __restrict__ T1, const short* __restrict__ W1T,
              const float* __restrict__ t1b,
              const short* __restrict__ T2, const short* __restrict__ W2T,
              const float* __restrict__ t2b,
              const int* __restrict__ idx1, const int* __restrict__ idx2,
              const int* __restrict__ counts, float* __restrict__ tsum)
{
    __shared__ char smem[33792];           // 32K sA + lsum/rlds
    const int b = blockIdx.x;
    if (b < 1280) {
        // t2 reg path: 16 xg x 80 cg (cg fastest -> B XCD-pinned)
        ce_reg64(T2, W2T, t2b, idx2, &counts[1], tsum, 40000,
                 b / 80, b % 80, (float*)smem, (int*)(smem + 1024));
    } else if (b < 1792) {
        const int b2 = b - 1280;           // head: 32 xg x 16 cg (xg fastest)
        ce_head2(H, WhT, head_b, hsum, b2 & 31, b2 >> 5,
                 smem, (float*)(smem + 32768));
    } else {
        const int b3 = b - 1792;           // t1: 8 xg x 32 cg (cg fastest)
        ce_core<256, 2, false, 128>(T1, W1T, t1b, idx1, &counts[0], tsum, 8000,
                                    b3 / 32, b3 % 32, smem,
                                    (float*)(smem + 32768), (int*)(smem + 33280));
    }
}

// ---- finalize: recompute label logits (tiny dots) + assemble loss --------
__global__ __launch_bounds__(256)
void finalize_kernel(const int* __restrict__ labels,
                     const short* __restrict__ H,  const short* __restrict__ WhT,
                     const float* __restrict__ head_b,
                     const short* __restrict__ T1, const short* __restrict__ W1T,
                     const float* __restrict__ t1b,
                     const short* __restrict__ T2, const short* __restrict__ W2T,
                     const float* __restrict__ t2b,
                     const float* __restrict__ hsum, const float* __restrict__ tsum,
                     float* __restrict__ out)
{
    const int r = blockIdx.x * 4 + (threadIdx.x >> 6);   // one wave per row
    const int l = threadIdx.x & 63;
    if (r >= NTOK) return;
    const int lab = labels[r];
    int labH = lab;
    if (lab >= 10000) labH = 2001; else if (lab >= 2000) labH = 2000;

    float d = 0.f;                                       // head label dot, K=1024
    {
        const short* a = H   + (size_t)r    * 1024 + l * 16;
        const short* b = WhT + (size_t)labH * 1024 + l * 16;
        #pragma unroll
        for (int u = 0; u < 2; ++u) {
            const short8 av = *reinterpret_cast<const short8*>(a + u * 8);
            const short8 bv = *reinterpret_cast<const short8*>(b + u * 8);
            #pragma unroll
            for (int e = 0; e < 8; ++e) d = fmaf(bf2f(av[e]), bf2f(bv[e]), d);
        }
    }
    float td = 0.f;                                      // tail label dot
    if (lab >= 2000) {
        const short* a; const short* b; int nl;
        if (lab < 10000) { a = T1 + (size_t)r * 256; b = W1T + (size_t)(lab - 2000) * 256; nl = 32; }
        else             { a = T2 + (size_t)r * 64;  b = W2T + (size_t)(lab - 10000) * 64; nl = 8; }
        if (l < nl) {
            const short8 av = *reinterpret_cast<const short8*>(a + l * 8);
            const short8 bv = *reinterpret_cast<const short8*>(b + l * 8);
            #pragma unroll
            for (int e = 0; e < 8; ++e) td = fmaf(bf2f(av[e]), bf2f(bv[e]), td);
        }
    }
    #pragma unroll
    for (int off = 32; off; off >>= 1) { d += __shfl_xor(d, off); td += __shfl_xor(td, off); }
    if (l == 0) {
        float loss = logf(hsum[r]) - (d + head_b[labH]);
        if (lab >= 2000) {
            const float tb = (lab < 10000) ? t1b[lab - 2000] : t2b[lab - 10000];
            loss += logf(tsum[r]) - (td + tb);
        }
        out[r] = loss;
    }
}

extern "C" void kernel_launch(void* const* d_in, const int* in_sizes, int n_in,
                              void* d_out, int out_size, void* d_ws, size_t ws_size,
                              hipStream_t stream) {
    (void)in_sizes; (void)n_in; (void)out_size; (void)ws_size;
    const float* X         = (const float*)d_in[0];
    const int*   labels    = (const int*)  d_in[1];
    const float* head_proj = (const float*)d_in[2];
    const float* head_w    = (const float*)d_in[3];
    const float* head_b    = (const float*)d_in[4];
    const float* t1p       = (const float*)d_in[5];
    const float* t1w       = (const float*)d_in[6];
    const float* t1b       = (const float*)d_in[7];
    const float* t2p       = (const float*)d_in[8];
    const float* t2w       = (const float*)d_in[9];
    const float* t2b       = (const float*)d_in[10];
    float* out = (float*)d_out;

    char* ws = (char*)d_ws;
    int*   counts = (int*)ws;                      // 2 ints
    int*   idx1   = (int*)(ws + 1024);
    int*   idx2   = (int*)(ws + 1024 + 16384);
    float* hsum   = (float*)(ws + 65536);          // 2 x 4096 f32
    float* tsum   = hsum + NTOK;

    short* p = (short*)(ws + 131072);
    short* Xb   = p; p += (size_t)NTOK * 1024;
    short* WhpT = p; p += (size_t)1024 * 1024;
    short* W1pT = p; p += (size_t)256  * 1024;
    short* W2pT = p; p += (size_t)64   * 1024;
    short* WhT  = p; p += (size_t)2048 * 1024;     // pad 2002->2048
    short* W1T  = p; p += (size_t)8192 * 256;      // pad 8000->8192
    short* W2T  = p; p += (size_t)40960 * 64;      // pad 40000->40960
    short* H    = p; p += (size_t)NTOK * 1024;
    short* T1   = p; p += (size_t)NTOK * 256;
    short* T2   = p; p += (size_t)NTOK * 64;

    hipMemsetAsync(counts, 0, 16, stream);
    hipMemsetAsync(hsum, 0, 2 * NTOK * sizeof(float), stream);

    prep_kernel<<<10064, 256, 0, stream>>>(X, Xb, head_proj, WhpT, t1p, W1pT,
                                           t2p, W2pT, head_w, WhT, t1w, W1T, t2w, W2T,
                                           labels, idx1, idx2, counts);
    // proj: 1344 cols -> 11 col-groups of 128; 32 row-groups of 128
    proj5<<<dim3(32, 11), 512, 0, stream>>>(Xb, WhpT, W1pT, W2pT, H, T1, T2);

    // fused CE: t2 (1280) + head (512) + t1 (256) = 2048 blocks, co-scheduled
    ce_fused<<<2048, 512, 0, stream>>>(H, WhT, head_b, hsum,
                                       T1, W1T, t1b, T2, W2T, t2b,
                                       idx1, idx2, counts, tsum);

    finalize_kernel<<<NTOK / 4, 256, 0, stream>>>(
        labels, H, WhT, head_b, T1, W1T, t1b, T2, W2T, t2b, hsum, tsum, out);
}

// Round 14
// 183.748 us; speedup vs baseline: 2.3292x; 1.0447x over previous
//
#include <hip/hip_runtime.h>
#include <hip/hip_bf16.h>
#include <math.h>

#define NTOK 4096
#define DIM  1024
#define LOG2E 1.4426950408889634f
#define LN2F  0.6931471805599453f

typedef __attribute__((ext_vector_type(8))) short short8;   // 8 bf16 = 4 VGPR
typedef __attribute__((ext_vector_type(4))) float f32x4;

extern "C" __device__ float __ocml_native_exp2_f32(float);  // raw v_exp_f32
#define EXP2(x) __ocml_native_exp2_f32(x)

__device__ __forceinline__ short f2bf(float f) {
    return __builtin_bit_cast(short, __float2bfloat16(f));
}
__device__ __forceinline__ float bf2f(short s) {
    unsigned u = ((unsigned)(unsigned short)s) << 16;
    return __builtin_bit_cast(float, u);
}
__device__ __forceinline__ float gelu_exact(float x) {
    return x * 0.5f * (1.0f + erff(x * 0.70710678118654752f));
}

// ------- fused prep: X->bf16 + 6 transposes (+log2e scale on CE W) --------
__device__ __forceinline__
void transpose_tile(const float* __restrict__ src, short* __restrict__ dst,
                    int K, int V, int Vpad, int vt, int kt, float scale)
{
    __shared__ float tile[32][33];
    const int v0 = vt * 32, k0 = kt * 32;
    const int tx = threadIdx.x & 31, ty = threadIdx.x >> 5;   // 32 x 8
    #pragma unroll
    for (int i = 0; i < 4; ++i) {
        const int k = k0 + ty + 8 * i, v = v0 + tx;
        tile[ty + 8 * i][tx] = (k < K && v < V) ? src[(size_t)k * V + v] : 0.f;
    }
    __syncthreads();
    #pragma unroll
    for (int i = 0; i < 4; ++i) {
        const int v = v0 + ty + 8 * i, k = k0 + tx;
        if (v < Vpad && k < K) dst[(size_t)v * K + k] = f2bf(tile[tx][ty + 8 * i] * scale);
    }
}

__global__ __launch_bounds__(256)
void prep_kernel(const float* __restrict__ X, short* __restrict__ Xb,
                 const float* __restrict__ hp,  short* __restrict__ WhpT,
                 const float* __restrict__ t1p, short* __restrict__ W1pT,
                 const float* __restrict__ t2p, short* __restrict__ W2pT,
                 const float* __restrict__ hw,  short* __restrict__ WhT,
                 const float* __restrict__ t1w, short* __restrict__ W1T,
                 const float* __restrict__ t2w, short* __restrict__ W2T,
                 const int* __restrict__ labels,
                 int* __restrict__ idx1, int* __restrict__ idx2,
                 int* __restrict__ counts)
{
    int b = blockIdx.x;
    if (b < 2048) {                       // X fp32 -> bf16 (4096x1024)
        const size_t idx = ((size_t)b * 256 + threadIdx.x) * 8;
        const float4 a = *reinterpret_cast<const float4*>(X + idx);
        const float4 c = *reinterpret_cast<const float4*>(X + idx + 4);
        short8 v;
        v[0] = f2bf(a.x); v[1] = f2bf(a.y); v[2] = f2bf(a.z); v[3] = f2bf(a.w);
        v[4] = f2bf(c.x); v[5] = f2bf(c.y); v[6] = f2bf(c.z); v[7] = f2bf(c.w);
        *reinterpret_cast<short8*>(Xb + idx) = v;
        return;
    }
    b -= 2048;
    if (b < 1024) { transpose_tile(hp,  WhpT, 1024, 1024,  1024,  b % 32,   b / 32,   1.0f);  return; }
    b -= 1024;
    if (b < 256)  { transpose_tile(t1p, W1pT, 1024, 256,   256,   b % 8,    b / 8,    1.0f);  return; }
    b -= 256;
    if (b < 64)   { transpose_tile(t2p, W2pT, 1024, 64,    64,    b % 2,    b / 2,    1.0f);  return; }
    b -= 64;
    if (b < 2048) { transpose_tile(hw,  WhT,  1024, 2002,  2048,  b % 64,   b / 64,   LOG2E); return; }
    b -= 2048;
    if (b < 2048) { transpose_tile(t1w, W1T,  256,  8000,  8192,  b % 256,  b / 256,  LOG2E); return; }
    b -= 2048;
    if (b < 2560) { transpose_tile(t2w, W2T,  64,  40000,  40960, b % 1280, b / 1280, LOG2E); return; }
    b -= 2560;
    {   // compaction: 16 blocks x 256 threads = 4096 rows
        const int i = b * 256 + threadIdx.x;
        const int lab = labels[i];
        if (lab >= 2000 && lab < 10000) idx1[atomicAdd(&counts[0], 1)] = i;
        else if (lab >= 10000)          idx2[atomicAdd(&counts[1], 1)] = i;
    }
}

// ---- proj5: dbuf LDS A (static kh), B-stationary regs, gelu epilogue ------
__global__ __launch_bounds__(512, 2)
void proj5(const short* __restrict__ Xb,
           const short* __restrict__ WhpT, const short* __restrict__ W1pT,
           const short* __restrict__ W2pT,
           short* __restrict__ H, short* __restrict__ T1, short* __restrict__ T2)
{
    constexpr int KSTEP = 256, CHB = 32 * KSTEP * 2;   // 16 KB per buffer
    __shared__ char sA[2][CHB];
    const int tid = threadIdx.x, w = tid >> 6, l = tid & 63;
    const int arow = l & 15, kg = l >> 4;
    const int c_g = (blockIdx.y * 8 + w) * 16;
    const short* Bt; short* Pout; int Vout, cl; bool active = true;
    if (c_g < 1024)      { Bt = WhpT; Pout = H;  Vout = 1024; cl = c_g; }
    else if (c_g < 1280) { Bt = W1pT; Pout = T1; Vout = 256;  cl = c_g - 1024; }
    else if (c_g < 1344) { Bt = W2pT; Pout = T2; Vout = 64;   cl = c_g - 1280; }
    else                 { Bt = W2pT; Pout = T2; Vout = 64;   cl = 0; active = false; }

    short8 breg[32];                      // B stationary, 128 VGPR (static idx)
    const short* bp = Bt + (size_t)(cl + arow) * DIM + kg * 8;
    #pragma unroll
    for (int f = 0; f < 32; ++f) breg[f] = *reinterpret_cast<const short8*>(bp + f * 32);

    const int g0 = blockIdx.x * 128;
    short8 st8[2];
    auto load_chunk = [&](int rt, int kh) {
        #pragma unroll
        for (int j = 0; j < 2; ++j) {
            const int v = tid + j * 512;
            const int m = v >> 5, c8 = v & 31;
            st8[j] = *reinterpret_cast<const short8*>(
                Xb + (size_t)(g0 + rt * 32 + m) * DIM + kh * KSTEP + c8 * 8);
        }
    };
    auto store_chunk = [&](int buf) {
        char* base = &sA[buf][0];
        #pragma unroll
        for (int j = 0; j < 2; ++j) {
            const int v = tid + j * 512;
            const int m = v >> 5, c8 = v & 31;
            *reinterpret_cast<short8*>(
                base + (((m * KSTEP + c8 * 8) * 2) ^ ((m & 7) << 4))) = st8[j];
        }
    };

    load_chunk(0, 0); store_chunk(0); __syncthreads();
    f32x4 acc[2] = {(f32x4){0.f,0.f,0.f,0.f}, (f32x4){0.f,0.f,0.f,0.f}};
    for (int rt = 0; rt < 4; ++rt) {
        #pragma unroll
        for (int kh = 0; kh < 4; ++kh) {
            const int buf = kh & 1;                       // compile-time parity
            const bool last = (rt == 3) && (kh == 3);
            if (!last) load_chunk(kh < 3 ? rt : rt + 1, (kh + 1) & 3);
            const char* base = &sA[buf][0];
            #pragma unroll
            for (int f = 0; f < 8; ++f) {
                const short8 af0 = *reinterpret_cast<const short8*>(
                    base + (((arow * KSTEP + f * 32 + kg * 8) * 2) ^ ((arow & 7) << 4)));
                const short8 af1 = *reinterpret_cast<const short8*>(
                    base + ((((16 + arow) * KSTEP + f * 32 + kg * 8) * 2) ^ ((arow & 7) << 4)));
                acc[0] = __builtin_amdgcn_mfma_f32_16x16x32_bf16(af0, breg[kh * 8 + f], acc[0], 0, 0, 0);
                acc[1] = __builtin_amdgcn_mfma_f32_16x16x32_bf16(af1, breg[kh * 8 + f], acc[1], 0, 0, 0);
            }
            if (kh == 3) {
                if (active) {
                    #pragma unroll
                    for (int mr = 0; mr < 2; ++mr)
                        #pragma unroll
                        for (int r = 0; r < 4; ++r)
                            Pout[(size_t)(g0 + rt * 32 + mr * 16 + kg * 4 + r) * Vout + cl + arow] =
                                f2bf(gelu_exact(acc[mr][r]));
                }
                acc[0] = (f32x4){0.f,0.f,0.f,0.f};
                acc[1] = (f32x4){0.f,0.f,0.f,0.f};
            }
            if (!last) store_chunk(buf ^ 1);
            __syncthreads();
        }
    }
}

// ---- ce_core: dbuf LDS A (static kh), B-stationary, 1-inst exp2 epilogue --
// B pre-scaled by log2e; cb[col] = exp(bias[col]) (0 masks pad cols).
template<int K, int NT, bool IDENT, int RPG>
__device__ __forceinline__
void ce_core(const short* __restrict__ A, const short* __restrict__ Bt,
             const float* __restrict__ bias, const int* __restrict__ rows,
             const int* __restrict__ countp, float* __restrict__ sum_acc,
             int V, int bx, int by,
             char* __restrict__ sA, float* __restrict__ lsum, int* __restrict__ rlds)
{
    constexpr int KSTEP = (K > 256) ? 256 : K;
    constexpr int NKH   = K / KSTEP;
    constexpr int NKFS  = KSTEP / 32;
    constexpr int NKF   = K / 32;
    constexpr int CHB   = 32 * KSTEP * 2;
    constexpr int NV8   = 32 * KSTEP / 8;
    constexpr int VPT   = (NV8 + 511) / 512;

    const int cnt = IDENT ? NTOK : *countp;
    const int g0 = bx * RPG;
    if (g0 >= cnt) return;
    const int ng = min(RPG, cnt - g0);
    const int tid = threadIdx.x;
    const int w = tid >> 6, l = tid & 63;
    const int arow = l & 15, kg = l >> 4;

    for (int t = tid; t < RPG; t += 512) {
        lsum[t] = 0.f;
        rlds[t] = IDENT ? (g0 + t) : rows[min(g0 + t, cnt - 1)];
    }

    int ct[NT]; float cb[NT]; short8 breg[NT][NKF];
    #pragma unroll
    for (int t = 0; t < NT; ++t) {
        ct[t] = (by * 8 + w) * (16 * NT) + t * 16;
        const int col = ct[t] + arow;
        cb[t] = (col < V) ? __expf(bias[col]) : 0.f;
        const short* bp = Bt + (size_t)(ct[t] + arow) * K + kg * 8;
        #pragma unroll
        for (int f = 0; f < NKF; ++f)
            breg[t][f] = *reinterpret_cast<const short8*>(bp + f * 32);
    }
    __syncthreads();

    const int NRT = (ng + 31) / 32;

    short8 st8[VPT];
    auto load_chunk = [&](int c) {
        const int rt = c / NKH, kh = c % NKH, rb = rt * 32;
        #pragma unroll
        for (int j = 0; j < VPT; ++j) {
            const int v = tid + j * 512;
            if (v < NV8) {
                const int m = v / (KSTEP / 8), c8 = v % (KSTEP / 8);
                st8[j] = *reinterpret_cast<const short8*>(
                    A + (size_t)rlds[min(rb + m, RPG - 1)] * K + kh * KSTEP + c8 * 8);
            }
        }
    };
    auto store_chunk = [&](int buf) {
        char* base = sA + buf * CHB;
        #pragma unroll
        for (int j = 0; j < VPT; ++j) {
            const int v = tid + j * 512;
            if (v < NV8) {
                const int m = v / (KSTEP / 8), c8 = v % (KSTEP / 8);
                *reinterpret_cast<short8*>(
                    base + (((m * KSTEP + c8 * 8) * 2) ^ ((m & 7) << 4))) = st8[j];
            }
        }
    };

    load_chunk(0); store_chunk(0); __syncthreads();

    f32x4 acc[2][NT];
    #pragma unroll
    for (int mr = 0; mr < 2; ++mr)
        #pragma unroll
        for (int t = 0; t < NT; ++t) acc[mr][t] = (f32x4){0.f,0.f,0.f,0.f};

    for (int rt = 0; rt < NRT; ++rt) {
        #pragma unroll
        for (int kh = 0; kh < NKH; ++kh) {
            const int c   = rt * NKH + kh;
            const int buf = (NKH > 1) ? (kh & 1) : (rt & 1);
            const bool last = (c + 1 == NRT * NKH);
            if (!last) load_chunk(c + 1);
            const char* base = sA + buf * CHB;
            #pragma unroll
            for (int f = 0; f < NKFS; ++f) {
                const short8 af0 = *reinterpret_cast<const short8*>(
                    base + (((arow * KSTEP + f * 32 + kg * 8) * 2) ^ ((arow & 7) << 4)));
                const short8 af1 = *reinterpret_cast<const short8*>(
                    base + ((((16 + arow) * KSTEP + f * 32 + kg * 8) * 2) ^ ((arow & 7) << 4)));
                #pragma unroll
                for (int t = 0; t < NT; ++t) {
                    acc[0][t] = __builtin_amdgcn_mfma_f32_16x16x32_bf16(
                        af0, breg[t][kh * NKFS + f], acc[0][t], 0, 0, 0);
                    acc[1][t] = __builtin_amdgcn_mfma_f32_16x16x32_bf16(
                        af1, breg[t][kh * NKFS + f], acc[1][t], 0, 0, 0);
                }
            }
            if (kh == NKH - 1) {
                const int rb = rt * 32;
                #pragma unroll
                for (int mr = 0; mr < 2; ++mr) {
                    float sacc[4] = {0.f, 0.f, 0.f, 0.f};
                    #pragma unroll
                    for (int t = 0; t < NT; ++t)
                        #pragma unroll
                        for (int r = 0; r < 4; ++r)
                            sacc[r] = fmaf(EXP2(acc[mr][t][r]), cb[t], sacc[r]);
                    #pragma unroll
                    for (int r = 0; r < 4; ++r) {
                        float v = sacc[r];
                        v += __shfl_xor(v, 1); v += __shfl_xor(v, 2);
                        v += __shfl_xor(v, 4); v += __shfl_xor(v, 8);
                        if (arow == 0) atomicAdd(&lsum[rb + mr * 16 + kg * 4 + r], v);
                    }
                    #pragma unroll
                    for (int t = 0; t < NT; ++t) acc[mr][t] = (f32x4){0.f,0.f,0.f,0.f};
                }
            }
            if (!last) store_chunk(buf ^ 1);
            __syncthreads();
        }
    }
    for (int t = tid; t < ng; t += 512)
        atomicAdd(&sum_acc[rlds[t]], lsum[t]);
}

// ---- t2 register path: K=64, barrier-free 8-tile ping-pong row loop ------
__device__ __forceinline__
void ce_reg64(const short* __restrict__ A, const short* __restrict__ Bt,
              const float* __restrict__ bias, const int* __restrict__ rows,
              const int* __restrict__ countp, float* __restrict__ sum_acc,
              int V, int bx, int by,
              float* __restrict__ lsum, int* __restrict__ rlds)
{
    constexpr int NT = 4, RPG = 256;
    const int cnt = *countp;
    const int g0 = bx * RPG;
    if (g0 >= cnt) return;
    const int ng = min(RPG, cnt - g0);
    const int tid = threadIdx.x;
    const int w = tid >> 6, l = tid & 63;
    const int arow = l & 15, kg = l >> 4;

    for (int t = tid; t < RPG; t += 512) {
        lsum[t] = 0.f;
        rlds[t] = rows[min(g0 + t, cnt - 1)];
    }

    int ct[NT]; float cb[NT]; short8 breg[NT][2];
    #pragma unroll
    for (int t = 0; t < NT; ++t) {
        ct[t] = (by * 8 + w) * 64 + t * 16;
        const int col = ct[t] + arow;
        cb[t] = (col < V) ? __expf(bias[col]) : 0.f;
        const short* bp = Bt + (size_t)(ct[t] + arow) * 64 + kg * 8;
        breg[t][0] = *reinterpret_cast<const short8*>(bp);
        breg[t][1] = *reinterpret_cast<const short8*>(bp + 32);
    }
    __syncthreads();                       // lsum/rlds ready

    auto load_tile = [&](int rt, short8 (&dst)[2][2]) {
        #pragma unroll
        for (int mr = 0; mr < 2; ++mr) {
            const int r = rlds[rt * 32 + mr * 16 + arow];
            const short* ap = A + (size_t)r * 64 + kg * 8;
            dst[mr][0] = *reinterpret_cast<const short8*>(ap);
            dst[mr][1] = *reinterpret_cast<const short8*>(ap + 32);
        }
    };
    auto compute_tile = [&](int rt, const short8 (&Ar)[2][2]) {
        f32x4 acc[2][NT];
        #pragma unroll
        for (int mr = 0; mr < 2; ++mr)
            #pragma unroll
            for (int t = 0; t < NT; ++t) acc[mr][t] = (f32x4){0.f,0.f,0.f,0.f};
        #pragma unroll
        for (int f = 0; f < 2; ++f)
            #pragma unroll
            for (int mr = 0; mr < 2; ++mr)
                #pragma unroll
                for (int t = 0; t < NT; ++t)
                    acc[mr][t] = __builtin_amdgcn_mfma_f32_16x16x32_bf16(
                        Ar[mr][f], breg[t][f], acc[mr][t], 0, 0, 0);
        const int rb = rt * 32;
        #pragma unroll
        for (int mr = 0; mr < 2; ++mr) {
            float sacc[4] = {0.f, 0.f, 0.f, 0.f};
            #pragma unroll
            for (int t = 0; t < NT; ++t)
                #pragma unroll
                for (int r = 0; r < 4; ++r)
                    sacc[r] = fmaf(EXP2(acc[mr][t][r]), cb[t], sacc[r]);
            #pragma unroll
            for (int r = 0; r < 4; ++r) {
                float v = sacc[r];
                v += __shfl_xor(v, 1); v += __shfl_xor(v, 2);
                v += __shfl_xor(v, 4); v += __shfl_xor(v, 8);
                if (arow == 0) atomicAdd(&lsum[rb + mr * 16 + kg * 4 + r], v);
            }
        }
    };

    short8 A0[2][2], A1[2][2];
    load_tile(0, A0);
    load_tile(1, A1);
    #pragma unroll
    for (int rt = 0; rt < 8; rt += 2) {    // barrier-free, 1-tile-ahead pipeline
        compute_tile(rt, A0);
        if (rt + 2 < 8) load_tile(rt + 2, A0);
        compute_tile(rt + 1, A1);
        if (rt + 3 < 8) load_tile(rt + 3, A1);
    }

    __syncthreads();
    for (int t = tid; t < ng; t += 512)
        atomicAdd(&sum_acc[rlds[t]], lsum[t]);
}

__global__ __launch_bounds__(512, 2)
void ce_head(const short* __restrict__ H, const short* __restrict__ WhT,
             const float* __restrict__ head_b, float* __restrict__ hsum)
{
    __shared__ char  sA[2][16384];
    __shared__ float lsum[128];
    __shared__ int   rlds[128];
    ce_core<1024, 1, true, 128>(H, WhT, head_b, nullptr, nullptr, hsum, 2002,
                                blockIdx.x, blockIdx.y, &sA[0][0], lsum, rlds);
}

#define NB_T2 1280   // 16 x-groups x 80 col-groups (by = b % 80 -> XCD-pinned B)
__global__ __launch_bounds__(512, 4)
void ce_tails(const short* __restrict__ T1, const short* __restrict__ W1T,
              const float* __restrict__ t1b,
              const short* __restrict__ T2, const short* __restrict__ W2T,
              const float* __restrict__ t2b,
              const int* __restrict__ idx1, const int* __restrict__ idx2,
              const int* __restrict__ counts, float* __restrict__ tsum)
{
    __shared__ char  sA[2][16384];
    __shared__ float lsum[256];
    __shared__ int   rlds[256];
    const int b = blockIdx.x;
    if (b < NB_T2) {
        // t2 reg path: by fastest (80 % 8 == 0 -> B XCD-pinned, L2-resident)
        ce_reg64(T2, W2T, t2b, idx2, &counts[1], tsum, 40000,
                 b / 80, b % 80, lsum, rlds);
    } else {
        const int b2 = b - NB_T2;          // t1 LDS path: 8 xg x 32 cg
        ce_core<256, 2, false, 128>(T1, W1T, t1b, idx1, &counts[0], tsum, 8000,
                                    b2 / 32, b2 % 32, &sA[0][0], lsum, rlds);
    }
}

// ---- finalize: label dots on log2e-scaled W (undo with *ln2) + loss ------
__global__ __launch_bounds__(256)
void finalize_kernel(const int* __restrict__ labels,
                     const short* __restrict__ H,  const short* __restrict__ WhT,
                     const float* __restrict__ head_b,
                     const short* __restrict__ T1, const short* __restrict__ W1T,
                     const float* __restrict__ t1b,
                     const short* __restrict__ T2, const short* __restrict__ W2T,
                     const float* __restrict__ t2b,
                     const float* __restrict__ hsum, const float* __restrict__ tsum,
                     float* __restrict__ out)
{
    const int r = blockIdx.x * 4 + (threadIdx.x >> 6);   // one wave per row
    const int l = threadIdx.x & 63;
    if (r >= NTOK) return;
    const int lab = labels[r];
    int labH = lab;
    if (lab >= 10000) labH = 2001; else if (lab >= 2000) labH = 2000;

    float d = 0.f;                                       // head label dot, K=1024
    {
        const short* a = H   + (size_t)r    * 1024 + l * 16;
        const short* b = WhT + (size_t)labH * 1024 + l * 16;
        #pragma unroll
        for (int u = 0; u < 2; ++u) {
            const short8 av = *reinterpret_cast<const short8*>(a + u * 8);
            const short8 bv = *reinterpret_cast<const short8*>(b + u * 8);
            #pragma unroll
            for (int e = 0; e < 8; ++e) d = fmaf(bf2f(av[e]), bf2f(bv[e]), d);
        }
    }
    float td = 0.f;                                      // tail label dot
    if (lab >= 2000) {
        const short* a; const short* b; int nl;
        if (lab < 10000) { a = T1 + (size_t)r * 256; b = W1T + (size_t)(lab - 2000) * 256; nl = 32; }
        else             { a = T2 + (size_t)r * 64;  b = W2T + (size_t)(lab - 10000) * 64; nl = 8; }
        if (l < nl) {
            const short8 av = *reinterpret_cast<const short8*>(a + l * 8);
            const short8 bv = *reinterpret_cast<const short8*>(b + l * 8);
            #pragma unroll
            for (int e = 0; e < 8; ++e) td = fmaf(bf2f(av[e]), bf2f(bv[e]), td);
        }
    }
    #pragma unroll
    for (int off = 32; off; off >>= 1) { d += __shfl_xor(d, off); td += __shfl_xor(td, off); }
    if (l == 0) {
        float loss = logf(hsum[r]) - (d * LN2F + head_b[labH]);
        if (lab >= 2000) {
            const float tb = (lab < 10000) ? t1b[lab - 2000] : t2b[lab - 10000];
            loss += logf(tsum[r]) - (td * LN2F + tb);
        }
        out[r] = loss;
    }
}

extern "C" void kernel_launch(void* const* d_in, const int* in_sizes, int n_in,
                              void* d_out, int out_size, void* d_ws, size_t ws_size,
                              hipStream_t stream) {
    (void)in_sizes; (void)n_in; (void)out_size; (void)ws_size;
    const float* X         = (const float*)d_in[0];
    const int*   labels    = (const int*)  d_in[1];
    const float* head_proj = (const float*)d_in[2];
    const float* head_w    = (const float*)d_in[3];
    const float* head_b    = (const float*)d_in[4];
    const float* t1p       = (const float*)d_in[5];
    const float* t1w       = (const float*)d_in[6];
    const float* t1b       = (const float*)d_in[7];
    const float* t2p       = (const float*)d_in[8];
    const float* t2w       = (const float*)d_in[9];
    const float* t2b       = (const float*)d_in[10];
    float* out = (float*)d_out;

    char* ws = (char*)d_ws;
    int*   counts = (int*)ws;                      // 2 ints
    int*   idx1   = (int*)(ws + 1024);
    int*   idx2   = (int*)(ws + 1024 + 16384);
    float* hsum   = (float*)(ws + 65536);          // 2 x 4096 f32
    float* tsum   = hsum + NTOK;

    short* p = (short*)(ws + 131072);
    short* Xb   = p; p += (size_t)NTOK * 1024;
    short* WhpT = p; p += (size_t)1024 * 1024;
    short* W1pT = p; p += (size_t)256  * 1024;
    short* W2pT = p; p += (size_t)64   * 1024;
    short* WhT  = p; p += (size_t)2048 * 1024;     // pad 2002->2048, *log2e
    short* W1T  = p; p += (size_t)8192 * 256;      // pad 8000->8192, *log2e
    short* W2T  = p; p += (size_t)40960 * 64;      // pad 40000->40960, *log2e
    short* H    = p; p += (size_t)NTOK * 1024;
    short* T1   = p; p += (size_t)NTOK * 256;
    short* T2   = p; p += (size_t)NTOK * 64;

    hipMemsetAsync(counts, 0, 16, stream);
    hipMemsetAsync(hsum, 0, 2 * NTOK * sizeof(float), stream);

    prep_kernel<<<10064, 256, 0, stream>>>(X, Xb, head_proj, WhpT, t1p, W1pT,
                                           t2p, W2pT, head_w, WhT, t1w, W1T, t2w, W2T,
                                           labels, idx1, idx2, counts);
    // proj: 1344 cols -> 11 col-groups of 128; 32 row-groups of 128
    proj5<<<dim3(32, 11), 512, 0, stream>>>(Xb, WhpT, W1pT, W2pT, H, T1, T2);

    // head: V=2002 (2048 -> 16 col-groups of 128), K=1024, RPG=128
    ce_head<<<dim3(32, 16), 512, 0, stream>>>(H, WhT, head_b, hsum);
    // tails: t2 reg-path (16 xg x 80 cg, RPG=256) then t1 LDS-path
    ce_tails<<<NB_T2 + 256, 512, 0, stream>>>(T1, W1T, t1b, T2, W2T, t2b,
                                              idx1, idx2, counts, tsum);

    finalize_kernel<<<NTOK / 4, 256, 0, stream>>>(
        labels, H, WhT, head_b, T1, W1T, t1b, T2, W2T, t2b, hsum, tsum, out);
}

// Round 15
// 180.377 us; speedup vs baseline: 2.3727x; 1.0187x over previous
//
#include <hip/hip_runtime.h>
#include <hip/hip_bf16.h>
#include <math.h>

#define NTOK 4096
#define DIM  1024
#define LOG2E 1.4426950408889634f
#define LN2F  0.6931471805599453f

typedef __attribute__((ext_vector_type(8))) short short8;   // 8 bf16 = 4 VGPR
typedef __attribute__((ext_vector_type(4))) float f32x4;

extern "C" __device__ float __ocml_native_exp2_f32(float);  // raw v_exp_f32
#define EXP2(x) __ocml_native_exp2_f32(x)

__device__ __forceinline__ short f2bf(float f) {
    return __builtin_bit_cast(short, __float2bfloat16(f));
}
__device__ __forceinline__ float bf2f(short s) {
    unsigned u = ((unsigned)(unsigned short)s) << 16;
    return __builtin_bit_cast(float, u);
}
__device__ __forceinline__ float gelu_exact(float x) {
    return x * 0.5f * (1.0f + erff(x * 0.70710678118654752f));
}

// ------- fused prep: X->bf16 + 6 transposes (+log2e scale on CE W) --------
__device__ __forceinline__
void transpose_tile(const float* __restrict__ src, short* __restrict__ dst,
                    int K, int V, int Vpad, int vt, int kt, float scale)
{
    __shared__ float tile[32][33];
    const int v0 = vt * 32, k0 = kt * 32;
    const int tx = threadIdx.x & 31, ty = threadIdx.x >> 5;   // 32 x 8
    #pragma unroll
    for (int i = 0; i < 4; ++i) {
        const int k = k0 + ty + 8 * i, v = v0 + tx;
        tile[ty + 8 * i][tx] = (k < K && v < V) ? src[(size_t)k * V + v] : 0.f;
    }
    __syncthreads();
    #pragma unroll
    for (int i = 0; i < 4; ++i) {
        const int v = v0 + ty + 8 * i, k = k0 + tx;
        if (v < Vpad && k < K) dst[(size_t)v * K + k] = f2bf(tile[tx][ty + 8 * i] * scale);
    }
}

__global__ __launch_bounds__(256)
void prep_kernel(const float* __restrict__ X, short* __restrict__ Xb,
                 const float* __restrict__ hp,  short* __restrict__ WhpT,
                 const float* __restrict__ t1p, short* __restrict__ W1pT,
                 const float* __restrict__ t2p, short* __restrict__ W2pT,
                 const float* __restrict__ hw,  short* __restrict__ WhT,
                 const float* __restrict__ t1w, short* __restrict__ W1T,
                 const float* __restrict__ t2w, short* __restrict__ W2T,
                 const int* __restrict__ labels,
                 int* __restrict__ idx1, int* __restrict__ idx2,
                 int* __restrict__ counts)
{
    int b = blockIdx.x;
    if (b < 2048) {                       // X fp32 -> bf16 (4096x1024)
        const size_t idx = ((size_t)b * 256 + threadIdx.x) * 8;
        const float4 a = *reinterpret_cast<const float4*>(X + idx);
        const float4 c = *reinterpret_cast<const float4*>(X + idx + 4);
        short8 v;
        v[0] = f2bf(a.x); v[1] = f2bf(a.y); v[2] = f2bf(a.z); v[3] = f2bf(a.w);
        v[4] = f2bf(c.x); v[5] = f2bf(c.y); v[6] = f2bf(c.z); v[7] = f2bf(c.w);
        *reinterpret_cast<short8*>(Xb + idx) = v;
        return;
    }
    b -= 2048;
    if (b < 1024) { transpose_tile(hp,  WhpT, 1024, 1024,  1024,  b % 32,   b / 32,   1.0f);  return; }
    b -= 1024;
    if (b < 256)  { transpose_tile(t1p, W1pT, 1024, 256,   256,   b % 8,    b / 8,    1.0f);  return; }
    b -= 256;
    if (b < 64)   { transpose_tile(t2p, W2pT, 1024, 64,    64,    b % 2,    b / 2,    1.0f);  return; }
    b -= 64;
    if (b < 2048) { transpose_tile(hw,  WhT,  1024, 2002,  2048,  b % 64,   b / 64,   LOG2E); return; }
    b -= 2048;
    if (b < 2048) { transpose_tile(t1w, W1T,  256,  8000,  8192,  b % 256,  b / 256,  LOG2E); return; }
    b -= 2048;
    if (b < 2560) { transpose_tile(t2w, W2T,  64,  40000,  40960, b % 1280, b / 1280, LOG2E); return; }
    b -= 2560;
    {   // compaction: 16 blocks x 256 threads = 4096 rows
        const int i = b * 256 + threadIdx.x;
        const int lab = labels[i];
        if (lab >= 2000 && lab < 10000) idx1[atomicAdd(&counts[0], 1)] = i;
        else if (lab >= 10000)          idx2[atomicAdd(&counts[1], 1)] = i;
    }
}

// ---- proj6: KSTEP=512 dbuf LDS A, B-stationary regs, gelu epilogue --------
// col space [0,1344): [0,1024)->H, [1024,1280)->T1, [1280,1344)->T2
__global__ __launch_bounds__(512, 2)
void proj6(const short* __restrict__ Xb,
           const short* __restrict__ WhpT, const short* __restrict__ W1pT,
           const short* __restrict__ W2pT,
           short* __restrict__ H, short* __restrict__ T1, short* __restrict__ T2)
{
    constexpr int KSTEP = 512, CHB = 32 * KSTEP * 2;   // 32 KB per buffer
    __shared__ char sA[2][CHB];                        // 64 KB
    const int tid = threadIdx.x, w = tid >> 6, l = tid & 63;
    const int arow = l & 15, kg = l >> 4;
    const int c_g = (blockIdx.y * 8 + w) * 16;
    const short* Bt; short* Pout; int Vout, cl; bool active = true;
    if (c_g < 1024)      { Bt = WhpT; Pout = H;  Vout = 1024; cl = c_g; }
    else if (c_g < 1280) { Bt = W1pT; Pout = T1; Vout = 256;  cl = c_g - 1024; }
    else if (c_g < 1344) { Bt = W2pT; Pout = T2; Vout = 64;   cl = c_g - 1280; }
    else                 { Bt = W2pT; Pout = T2; Vout = 64;   cl = 0; active = false; }

    short8 breg[32];                      // B stationary, 128 VGPR (static idx)
    const short* bp = Bt + (size_t)(cl + arow) * DIM + kg * 8;
    #pragma unroll
    for (int f = 0; f < 32; ++f) breg[f] = *reinterpret_cast<const short8*>(bp + f * 32);

    const int g0 = blockIdx.x * 128;
    short8 st8[4];
    auto load_chunk = [&](int rt, int kh) {
        #pragma unroll
        for (int j = 0; j < 4; ++j) {
            const int v = tid + j * 512;
            const int m = v >> 6, c8 = v & 63;
            st8[j] = *reinterpret_cast<const short8*>(
                Xb + (size_t)(g0 + rt * 32 + m) * DIM + kh * KSTEP + c8 * 8);
        }
    };
    auto store_chunk = [&](int buf) {
        char* base = &sA[buf][0];
        #pragma unroll
        for (int j = 0; j < 4; ++j) {
            const int v = tid + j * 512;
            const int m = v >> 6, c8 = v & 63;
            *reinterpret_cast<short8*>(
                base + (((m * KSTEP + c8 * 8) * 2) ^ ((m & 7) << 4))) = st8[j];
        }
    };

    load_chunk(0, 0); store_chunk(0); __syncthreads();
    f32x4 acc[2] = {(f32x4){0.f,0.f,0.f,0.f}, (f32x4){0.f,0.f,0.f,0.f}};
    for (int rt = 0; rt < 4; ++rt) {
        #pragma unroll
        for (int kh = 0; kh < 2; ++kh) {
            const int buf = kh;                           // compile-time parity
            const bool last = (rt == 3) && (kh == 1);
            if (!last) load_chunk(kh == 0 ? rt : rt + 1, kh ^ 1);
            const char* base = &sA[buf][0];
            #pragma unroll
            for (int f = 0; f < 16; ++f) {
                const short8 af0 = *reinterpret_cast<const short8*>(
                    base + (((arow * KSTEP + f * 32 + kg * 8) * 2) ^ ((arow & 7) << 4)));
                const short8 af1 = *reinterpret_cast<const short8*>(
                    base + ((((16 + arow) * KSTEP + f * 32 + kg * 8) * 2) ^ ((arow & 7) << 4)));
                acc[0] = __builtin_amdgcn_mfma_f32_16x16x32_bf16(af0, breg[kh * 16 + f], acc[0], 0, 0, 0);
                acc[1] = __builtin_amdgcn_mfma_f32_16x16x32_bf16(af1, breg[kh * 16 + f], acc[1], 0, 0, 0);
            }
            if (kh == 1) {
                if (active) {
                    #pragma unroll
                    for (int mr = 0; mr < 2; ++mr)
                        #pragma unroll
                        for (int r = 0; r < 4; ++r)
                            Pout[(size_t)(g0 + rt * 32 + mr * 16 + kg * 4 + r) * Vout + cl + arow] =
                                f2bf(gelu_exact(acc[mr][r]));
                }
                acc[0] = (f32x4){0.f,0.f,0.f,0.f};
                acc[1] = (f32x4){0.f,0.f,0.f,0.f};
            }
            if (!last) store_chunk(buf ^ 1);
            __syncthreads();
        }
    }
}

// ---- ce_core: dbuf LDS A (KSTEP<=512), B-stationary, exp2 epilogue -------
// B pre-scaled by log2e; cb[col] = exp(bias[col]) (0 masks pad cols).
template<int K, int NT, bool IDENT, int RPG>
__device__ __forceinline__
void ce_core(const short* __restrict__ A, const short* __restrict__ Bt,
             const float* __restrict__ bias, const int* __restrict__ rows,
             const int* __restrict__ countp, float* __restrict__ sum_acc,
             int V, int bx, int by,
             char* __restrict__ sA, float* __restrict__ lsum, int* __restrict__ rlds)
{
    constexpr int KSTEP = (K > 512) ? 512 : K;
    constexpr int NKH   = K / KSTEP;
    constexpr int NKFS  = KSTEP / 32;
    constexpr int NKF   = K / 32;
    constexpr int CHB   = 32 * KSTEP * 2;
    constexpr int NV8   = 32 * KSTEP / 8;
    constexpr int VPT   = (NV8 + 511) / 512;

    const int cnt = IDENT ? NTOK : *countp;
    const int g0 = bx * RPG;
    if (g0 >= cnt) return;
    const int ng = min(RPG, cnt - g0);
    const int tid = threadIdx.x;
    const int w = tid >> 6, l = tid & 63;
    const int arow = l & 15, kg = l >> 4;

    for (int t = tid; t < RPG; t += 512) {
        lsum[t] = 0.f;
        rlds[t] = IDENT ? (g0 + t) : rows[min(g0 + t, cnt - 1)];
    }

    int ct[NT]; float cb[NT]; short8 breg[NT][NKF];
    #pragma unroll
    for (int t = 0; t < NT; ++t) {
        ct[t] = (by * 8 + w) * (16 * NT) + t * 16;
        const int col = ct[t] + arow;
        cb[t] = (col < V) ? __expf(bias[col]) : 0.f;
        const short* bp = Bt + (size_t)(ct[t] + arow) * K + kg * 8;
        #pragma unroll
        for (int f = 0; f < NKF; ++f)
            breg[t][f] = *reinterpret_cast<const short8*>(bp + f * 32);
    }
    __syncthreads();

    const int NRT = (ng + 31) / 32;

    short8 st8[VPT];
    auto load_chunk = [&](int c) {
        const int rt = c / NKH, kh = c % NKH, rb = rt * 32;
        #pragma unroll
        for (int j = 0; j < VPT; ++j) {
            const int v = tid + j * 512;
            if (v < NV8) {
                const int m = v / (KSTEP / 8), c8 = v % (KSTEP / 8);
                st8[j] = *reinterpret_cast<const short8*>(
                    A + (size_t)rlds[min(rb + m, RPG - 1)] * K + kh * KSTEP + c8 * 8);
            }
        }
    };
    auto store_chunk = [&](int buf) {
        char* base = sA + buf * CHB;
        #pragma unroll
        for (int j = 0; j < VPT; ++j) {
            const int v = tid + j * 512;
            if (v < NV8) {
                const int m = v / (KSTEP / 8), c8 = v % (KSTEP / 8);
                *reinterpret_cast<short8*>(
                    base + (((m * KSTEP + c8 * 8) * 2) ^ ((m & 7) << 4))) = st8[j];
            }
        }
    };

    load_chunk(0); store_chunk(0); __syncthreads();

    f32x4 acc[2][NT];
    #pragma unroll
    for (int mr = 0; mr < 2; ++mr)
        #pragma unroll
        for (int t = 0; t < NT; ++t) acc[mr][t] = (f32x4){0.f,0.f,0.f,0.f};

    for (int rt = 0; rt < NRT; ++rt) {
        #pragma unroll
        for (int kh = 0; kh < NKH; ++kh) {
            const int c   = rt * NKH + kh;
            const int buf = (NKH > 1) ? (kh & 1) : (rt & 1);
            const bool last = (c + 1 == NRT * NKH);
            if (!last) load_chunk(c + 1);
            const char* base = sA + buf * CHB;
            #pragma unroll
            for (int f = 0; f < NKFS; ++f) {
                const short8 af0 = *reinterpret_cast<const short8*>(
                    base + (((arow * KSTEP + f * 32 + kg * 8) * 2) ^ ((arow & 7) << 4)));
                const short8 af1 = *reinterpret_cast<const short8*>(
                    base + ((((16 + arow) * KSTEP + f * 32 + kg * 8) * 2) ^ ((arow & 7) << 4)));
                #pragma unroll
                for (int t = 0; t < NT; ++t) {
                    acc[0][t] = __builtin_amdgcn_mfma_f32_16x16x32_bf16(
                        af0, breg[t][kh * NKFS + f], acc[0][t], 0, 0, 0);
                    acc[1][t] = __builtin_amdgcn_mfma_f32_16x16x32_bf16(
                        af1, breg[t][kh * NKFS + f], acc[1][t], 0, 0, 0);
                }
            }
            if (kh == NKH - 1) {
                const int rb = rt * 32;
                #pragma unroll
                for (int mr = 0; mr < 2; ++mr) {
                    float sacc[4] = {0.f, 0.f, 0.f, 0.f};
                    #pragma unroll
                    for (int t = 0; t < NT; ++t)
                        #pragma unroll
                        for (int r = 0; r < 4; ++r)
                            sacc[r] = fmaf(EXP2(acc[mr][t][r]), cb[t], sacc[r]);
                    #pragma unroll
                    for (int r = 0; r < 4; ++r) {
                        float v = sacc[r];
                        v += __shfl_xor(v, 1); v += __shfl_xor(v, 2);
                        v += __shfl_xor(v, 4); v += __shfl_xor(v, 8);
                        if (arow == 0) atomicAdd(&lsum[rb + mr * 16 + kg * 4 + r], v);
                    }
                    #pragma unroll
                    for (int t = 0; t < NT; ++t) acc[mr][t] = (f32x4){0.f,0.f,0.f,0.f};
                }
            }
            if (!last) store_chunk(buf ^ 1);
            __syncthreads();
        }
    }
    for (int t = tid; t < ng; t += 512)
        atomicAdd(&sum_acc[rlds[t]], lsum[t]);
}

// ---- t2 register path: K=64, barrier-free, 3-buffer 2-ahead pipeline -----
__device__ __forceinline__
void ce_reg64(const short* __restrict__ A, const short* __restrict__ Bt,
              const float* __restrict__ bias, const int* __restrict__ rows,
              const int* __restrict__ countp, float* __restrict__ sum_acc,
              int V, int bx, int by,
              float* __restrict__ lsum, int* __restrict__ rlds)
{
    constexpr int NT = 4, RPG = 256;
    const int cnt = *countp;
    const int g0 = bx * RPG;
    if (g0 >= cnt) return;
    const int ng = min(RPG, cnt - g0);
    const int tid = threadIdx.x;
    const int w = tid >> 6, l = tid & 63;
    const int arow = l & 15, kg = l >> 4;

    for (int t = tid; t < RPG; t += 512) {
        lsum[t] = 0.f;
        rlds[t] = rows[min(g0 + t, cnt - 1)];
    }

    int ct[NT]; float cb[NT]; short8 breg[NT][2];
    #pragma unroll
    for (int t = 0; t < NT; ++t) {
        ct[t] = (by * 8 + w) * 64 + t * 16;
        const int col = ct[t] + arow;
        cb[t] = (col < V) ? __expf(bias[col]) : 0.f;
        const short* bp = Bt + (size_t)(ct[t] + arow) * 64 + kg * 8;
        breg[t][0] = *reinterpret_cast<const short8*>(bp);
        breg[t][1] = *reinterpret_cast<const short8*>(bp + 32);
    }
    __syncthreads();                       // lsum/rlds ready

    auto load_tile = [&](int rt, short8 (&dst)[2][2]) {
        #pragma unroll
        for (int mr = 0; mr < 2; ++mr) {
            const int r = rlds[rt * 32 + mr * 16 + arow];
            const short* ap = A + (size_t)r * 64 + kg * 8;
            dst[mr][0] = *reinterpret_cast<const short8*>(ap);
            dst[mr][1] = *reinterpret_cast<const short8*>(ap + 32);
        }
    };
    auto compute_tile = [&](int rt, const short8 (&Ar)[2][2]) {
        f32x4 acc[2][NT];
        #pragma unroll
        for (int mr = 0; mr < 2; ++mr)
            #pragma unroll
            for (int t = 0; t < NT; ++t) acc[mr][t] = (f32x4){0.f,0.f,0.f,0.f};
        #pragma unroll
        for (int f = 0; f < 2; ++f)
            #pragma unroll
            for (int mr = 0; mr < 2; ++mr)
                #pragma unroll
                for (int t = 0; t < NT; ++t)
                    acc[mr][t] = __builtin_amdgcn_mfma_f32_16x16x32_bf16(
                        Ar[mr][f], breg[t][f], acc[mr][t], 0, 0, 0);
        const int rb = rt * 32;
        #pragma unroll
        for (int mr = 0; mr < 2; ++mr) {
            float sacc[4] = {0.f, 0.f, 0.f, 0.f};
            #pragma unroll
            for (int t = 0; t < NT; ++t)
                #pragma unroll
                for (int r = 0; r < 4; ++r)
                    sacc[r] = fmaf(EXP2(acc[mr][t][r]), cb[t], sacc[r]);
            #pragma unroll
            for (int r = 0; r < 4; ++r) {
                float v = sacc[r];
                v += __shfl_xor(v, 1); v += __shfl_xor(v, 2);
                v += __shfl_xor(v, 4); v += __shfl_xor(v, 8);
                if (arow == 0) atomicAdd(&lsum[rb + mr * 16 + kg * 4 + r], v);
            }
        }
    };

    // 3-buffer rotation: when computing tile t, tiles t+1 and t+2 in flight.
    short8 A0[2][2], A1[2][2], A2[2][2];
    load_tile(0, A0);
    load_tile(1, A1);
    load_tile(2, A2);
    compute_tile(0, A0); load_tile(3, A0);
    compute_tile(1, A1); load_tile(4, A1);
    compute_tile(2, A2); load_tile(5, A2);
    compute_tile(3, A0); load_tile(6, A0);
    compute_tile(4, A1); load_tile(7, A1);
    compute_tile(5, A2);
    compute_tile(6, A0);
    compute_tile(7, A1);

    __syncthreads();
    for (int t = tid; t < ng; t += 512)
        atomicAdd(&sum_acc[rlds[t]], lsum[t]);
}

__global__ __launch_bounds__(512, 2)
void ce_head(const short* __restrict__ H, const short* __restrict__ WhT,
             const float* __restrict__ head_b, float* __restrict__ hsum)
{
    __shared__ char  sA[2][32768];         // KSTEP=512 dbuf (64 KB)
    __shared__ float lsum[128];
    __shared__ int   rlds[128];
    ce_core<1024, 1, true, 128>(H, WhT, head_b, nullptr, nullptr, hsum, 2002,
                                blockIdx.x, blockIdx.y, &sA[0][0], lsum, rlds);
}

#define NB_T2 1280   // 16 x-groups x 80 col-groups (by = b % 80 -> XCD-pinned B)
__global__ __launch_bounds__(512, 4)
void ce_tails(const short* __restrict__ T1, const short* __restrict__ W1T,
              const float* __restrict__ t1b,
              const short* __restrict__ T2, const short* __restrict__ W2T,
              const float* __restrict__ t2b,
              const int* __restrict__ idx1, const int* __restrict__ idx2,
              const int* __restrict__ counts, float* __restrict__ tsum)
{
    __shared__ char  sA[2][16384];
    __shared__ float lsum[256];
    __shared__ int   rlds[256];
    const int b = blockIdx.x;
    if (b < NB_T2) {
        // t2 reg path: by fastest (80 % 8 == 0 -> B XCD-pinned, L2-resident)
        ce_reg64(T2, W2T, t2b, idx2, &counts[1], tsum, 40000,
                 b / 80, b % 80, lsum, rlds);
    } else {
        const int b2 = b - NB_T2;          // t1 LDS path: 8 xg x 32 cg
        ce_core<256, 2, false, 128>(T1, W1T, t1b, idx1, &counts[0], tsum, 8000,
                                    b2 / 32, b2 % 32, &sA[0][0], lsum, rlds);
    }
}

// ---- finalize: label dots on log2e-scaled W (undo with *ln2) + loss ------
__global__ __launch_bounds__(256)
void finalize_kernel(const int* __restrict__ labels,
                     const short* __restrict__ H,  const short* __restrict__ WhT,
                     const float* __restrict__ head_b,
                     const short* __restrict__ T1, const short* __restrict__ W1T,
                     const float* __restrict__ t1b,
                     const short* __restrict__ T2, const short* __restrict__ W2T,
                     const float* __restrict__ t2b,
                     const float* __restrict__ hsum, const float* __restrict__ tsum,
                     float* __restrict__ out)
{
    const int r = blockIdx.x * 4 + (threadIdx.x >> 6);   // one wave per row
    const int l = threadIdx.x & 63;
    if (r >= NTOK) return;
    const int lab = labels[r];
    int labH = lab;
    if (lab >= 10000) labH = 2001; else if (lab >= 2000) labH = 2000;

    float d = 0.f;                                       // head label dot, K=1024
    {
        const short* a = H   + (size_t)r    * 1024 + l * 16;
        const short* b = WhT + (size_t)labH * 1024 + l * 16;
        #pragma unroll
        for (int u = 0; u < 2; ++u) {
            const short8 av = *reinterpret_cast<const short8*>(a + u * 8);
            const short8 bv = *reinterpret_cast<const short8*>(b + u * 8);
            #pragma unroll
            for (int e = 0; e < 8; ++e) d = fmaf(bf2f(av[e]), bf2f(bv[e]), d);
        }
    }
    float td = 0.f;                                      // tail label dot
    if (lab >= 2000) {
        const short* a; const short* b; int nl;
        if (lab < 10000) { a = T1 + (size_t)r * 256; b = W1T + (size_t)(lab - 2000) * 256; nl = 32; }
        else             { a = T2 + (size_t)r * 64;  b = W2T + (size_t)(lab - 10000) * 64; nl = 8; }
        if (l < nl) {
            const short8 av = *reinterpret_cast<const short8*>(a + l * 8);
            const short8 bv = *reinterpret_cast<const short8*>(b + l * 8);
            #pragma unroll
            for (int e = 0; e < 8; ++e) td = fmaf(bf2f(av[e]), bf2f(bv[e]), td);
        }
    }
    #pragma unroll
    for (int off = 32; off; off >>= 1) { d += __shfl_xor(d, off); td += __shfl_xor(td, off); }
    if (l == 0) {
        float loss = logf(hsum[r]) - (d * LN2F + head_b[labH]);
        if (lab >= 2000) {
            const float tb = (lab < 10000) ? t1b[lab - 2000] : t2b[lab - 10000];
            loss += logf(tsum[r]) - (td * LN2F + tb);
        }
        out[r] = loss;
    }
}

extern "C" void kernel_launch(void* const* d_in, const int* in_sizes, int n_in,
                              void* d_out, int out_size, void* d_ws, size_t ws_size,
                              hipStream_t stream) {
    (void)in_sizes; (void)n_in; (void)out_size; (void)ws_size;
    const float* X         = (const float*)d_in[0];
    const int*   labels    = (const int*)  d_in[1];
    const float* head_proj = (const float*)d_in[2];
    const float* head_w    = (const float*)d_in[3];
    const float* head_b    = (const float*)d_in[4];
    const float* t1p       = (const float*)d_in[5];
    const float* t1w       = (const float*)d_in[6];
    const float* t1b       = (const float*)d_in[7];
    const float* t2p       = (const float*)d_in[8];
    const float* t2w       = (const float*)d_in[9];
    const float* t2b       = (const float*)d_in[10];
    float* out = (float*)d_out;

    char* ws = (char*)d_ws;
    int*   counts = (int*)ws;                      // 2 ints
    int*   idx1   = (int*)(ws + 1024);
    int*   idx2   = (int*)(ws + 1024 + 16384);
    float* hsum   = (float*)(ws + 65536);          // 2 x 4096 f32
    float* tsum   = hsum + NTOK;

    short* p = (short*)(ws + 131072);
    short* Xb   = p; p += (size_t)NTOK * 1024;
    short* WhpT = p; p += (size_t)1024 * 1024;
    short* W1pT = p; p += (size_t)256  * 1024;
    short* W2pT = p; p += (size_t)64   * 1024;
    short* WhT  = p; p += (size_t)2048 * 1024;     // pad 2002->2048, *log2e
    short* W1T  = p; p += (size_t)8192 * 256;      // pad 8000->8192, *log2e
    short* W2T  = p; p += (size_t)40960 * 64;      // pad 40000->40960, *log2e
    short* H    = p; p += (size_t)NTOK * 1024;
    short* T1   = p; p += (size_t)NTOK * 256;
    short* T2   = p; p += (size_t)NTOK * 64;

    hipMemsetAsync(counts, 0, 16, stream);
    hipMemsetAsync(hsum, 0, 2 * NTOK * sizeof(float), stream);

    prep_kernel<<<10064, 256, 0, stream>>>(X, Xb, head_proj, WhpT, t1p, W1pT,
                                           t2p, W2pT, head_w, WhT, t1w, W1T, t2w, W2T,
                                           labels, idx1, idx2, counts);
    // proj: 1344 cols -> 11 col-groups of 128; 32 row-groups of 128
    proj6<<<dim3(32, 11), 512, 0, stream>>>(Xb, WhpT, W1pT, W2pT, H, T1, T2);

    // head: V=2002 (2048 -> 16 col-groups of 128), K=1024 (KSTEP=512), RPG=128
    ce_head<<<dim3(32, 16), 512, 0, stream>>>(H, WhT, head_b, hsum);
    // tails: t2 reg-path (16 xg x 80 cg, RPG=256, 2-ahead) then t1 LDS-path
    ce_tails<<<NB_T2 + 256, 512, 0, stream>>>(T1, W1T, t1b, T2, W2T, t2b,
                                              idx1, idx2, counts, tsum);

    finalize_kernel<<<NTOK / 4, 256, 0, stream>>>(
        labels, H, WhT, head_b, T1, W1T, t1b, T2, W2T, t2b, hsum, tsum, out);
}